// Round 3
// baseline (2728.859 us; speedup 1.0000x reference)
//
#include <hip/hip_runtime.h>
#include <hip/hip_fp16.h>

#define NN 50000
#define EE 800000
#define DIM 128
#define OUTC 20
#define LL 7
#define LE (LL*EE)
#define LN (LL*NN)
#define BN_EPS 1e-5f
#define LSTRIDE 136     // bf16 elems per LDS row
#define NREP 64         // BN stat replicas
#define NBUK 196        // coarse buckets of 256 dsts per layer
#define GMS  200        // padded Gm stride
#define NBLK 200        // edge-blocks per layer (EE/NBLK = 4000)
#define CH   4000
#define SCN  (LL*NBUK*NBLK)   // 274400 scan entries
#define FSCAP 4864      // fsort LDS staging capacity

typedef __attribute__((ext_vector_type(8))) short short8;
typedef __attribute__((ext_vector_type(4))) float f32x4;

static __device__ __forceinline__ float sigm(float z){ return 1.0f/(1.0f+expf(-z)); }
static __device__ __forceinline__ unsigned short f2bf(float f){
  unsigned int u = __float_as_uint(f);
  u += 0x7FFF + ((u>>16)&1);            // RNE
  return (unsigned short)(u>>16);
}
static __device__ __forceinline__ float bf2f(unsigned short s){
  return __uint_as_float(((unsigned int)s)<<16);
}

// ======== preprocessing: counting sort, all atomics in LDS, pure streaming ========

__global__ __launch_bounds__(256) void k_bh(const int* __restrict__ ei,
    int* __restrict__ Gm){
  int l = blockIdx.x / NBLK, b = blockIdx.x - l*NBLK;
  int t = threadIdx.x;
  __shared__ int h[NBUK];
  if (t<NBUK) h[t]=0;
  const int* dsts = ei + (size_t)(2*l+1)*EE + b*CH;
  int dv[16];
  #pragma unroll
  for (int i=0;i<16;i++){
    int k = t + i*256;
    if (k<CH) dv[i] = __builtin_nontemporal_load(dsts+k);
  }
  __syncthreads();
  #pragma unroll
  for (int i=0;i<16;i++){
    int k = t + i*256;
    if (k<CH) atomicAdd(&h[dv[i]>>8], 1);
  }
  __syncthreads();
  int* g = Gm + (size_t)(l*NBLK+b)*GMS;
  if (t<NBUK) g[t]=h[t];
}

__global__ __launch_bounds__(256) void k_scan1p(const int* __restrict__ Gm,
    int* __restrict__ part, int* __restrict__ bsums){
  __shared__ int s[256];
  int t = threadIdx.x;
  int base = blockIdx.x*4096 + t*16;
  int v[16]; int sum = 0;
  #pragma unroll
  for (int i=0;i<16;i++){
    int idx = base+i; int val = 0;
    if (idx < SCN){
      int l = idx/(NBUK*NBLK);
      int r = idx - l*(NBUK*NBLK);
      int buk = r/NBLK, b = r - buk*NBLK;
      val = Gm[(size_t)(l*NBLK+b)*GMS + buk];
    }
    v[i]=val; sum+=val;
  }
  s[t]=sum; __syncthreads();
  for (int off=1; off<256; off<<=1){
    int x = (t>=off)? s[t-off] : 0;
    __syncthreads(); s[t]+=x; __syncthreads();
  }
  if (t==255) bsums[blockIdx.x] = s[255];
  int run = s[t]-sum;
  #pragma unroll
  for (int i=0;i<16;i++){ if (base+i<SCN) part[base+i]=run; run += v[i]; }
}

__global__ __launch_bounds__(1024) void k_scan2(int* bsums, int nb){
  __shared__ int s[1024];
  int t=threadIdx.x;
  int v = (t<nb)? bsums[t]:0;
  s[t]=v; __syncthreads();
  for (int off=1; off<1024; off<<=1){
    int x=(t>=off)? s[t-off]:0; __syncthreads(); s[t]+=x; __syncthreads();
  }
  if (t<nb) bsums[t] = s[t]-v;
}

__global__ void k_scan3(int* __restrict__ S, const int* __restrict__ bsums){
  int gid = blockIdx.x*256+threadIdx.x;
  if (gid < SCN) S[gid] += bsums[gid>>12];
  if (gid==0) S[SCN]=LE;
}

// P3: LDS counting-sort by bucket with FINAL payload stored at placement.
__global__ __launch_bounds__(256) void k_bscatter(const int* __restrict__ ei,
    const float* __restrict__ ew, const int* __restrict__ S,
    const int* __restrict__ Gm,
    unsigned int* __restrict__ btmpP, unsigned char* __restrict__ btmpD){
  int l = blockIdx.x / NBLK, b = blockIdx.x - l*NBLK;
  int t = threadIdx.x;
  __shared__ int bstart[NBUK], cur[NBUK], runb[NBUK];
  __shared__ int ps[256];
  __shared__ unsigned int  ebP[CH];     // 16 KB: src16|halfw16
  __shared__ unsigned short ebM[CH];    // 8 KB:  dlow8|buk8
  const int* srcs = ei + (size_t)(2*l)*EE + b*CH;
  const int* dsts = ei + (size_t)(2*l+1)*EE + b*CH;
  const float* wsrc = ew + (size_t)l*EE + b*CH;
  int sv[16], dv[16]; float wv[16];
  #pragma unroll
  for (int i=0;i<16;i++){
    int k = t + i*256;
    if (k<CH){
      sv[i] = __builtin_nontemporal_load(srcs+k);
      dv[i] = __builtin_nontemporal_load(dsts+k);
      wv[i] = __builtin_nontemporal_load(wsrc+k);
    }
  }
  int v = (t<NBUK)? Gm[(size_t)(l*NBLK+b)*GMS + t] : 0;
  ps[t]=v; __syncthreads();
  for (int o=1;o<256;o<<=1){ int x=(t>=o)?ps[t-o]:0; __syncthreads(); ps[t]+=x; __syncthreads(); }
  if (t<NBUK){ bstart[t]=ps[t]-v; cur[t]=ps[t]-v; runb[t] = S[(size_t)(l*NBUK+t)*NBLK + b]; }
  __syncthreads();
  #pragma unroll
  for (int i=0;i<16;i++){
    int k = t + i*256;
    if (k<CH){
      int buk = dv[i]>>8;
      int pos = atomicAdd(&cur[buk],1);
      unsigned short hw = __half_as_ushort(__float2half(wv[i]));
      ebP[pos] = (unsigned)sv[i] | ((unsigned)hw<<16);
      ebM[pos] = (unsigned short)((dv[i]&255) | (buk<<8));
    }
  }
  __syncthreads();
  for (int k=t;k<CH;k+=256){
    unsigned short m = ebM[k];
    int buk = m>>8;
    int gp = runb[buk] + (k - bstart[buk]);
    btmpP[gp] = ebP[k];
    btmpD[gp] = (unsigned char)(m&255);
  }
}

// P4: per-bucket count+scan; scatter staged through LDS for coalesced writeback.
__global__ __launch_bounds__(256) void k_fsort(const unsigned int* __restrict__ btmpP,
    const unsigned char* __restrict__ btmpD, const int* __restrict__ S,
    unsigned int* __restrict__ sedge, int* __restrict__ offs){
  int lbuk = blockIdx.x;
  int l = lbuk/NBUK, bl = lbuk - l*NBUK;
  int t = threadIdx.x;
  int base = S[(size_t)lbuk*NBLK];
  int end  = S[(size_t)(lbuk+1)*NBLK];
  int nE = end - base;
  __shared__ int cnt[256], sc[256];
  __shared__ unsigned int stg[FSCAP];
  cnt[t]=0;
  __syncthreads();
  for (int k=t; k<nE; k+=256) atomicAdd(&cnt[btmpD[base+k]], 1);
  __syncthreads();
  int c = cnt[t];
  sc[t]=c;
  __syncthreads();
  for (int o=1;o<256;o<<=1){
    int v = (t>=o)? sc[t-o]:0;
    __syncthreads();
    sc[t]+=v;
    __syncthreads();
  }
  int excl = sc[t]-c;
  {
    int node = bl*256+t;
    if (node<NN) offs[(size_t)l*NN+node] = base + excl;
  }
  if (lbuk==0 && t==255) offs[LN]=LE;
  if (nE <= FSCAP){
    cnt[t] = excl;                 // LDS-relative running cursor
    __syncthreads();
    for (int k=t; k<nE; k+=256){
      int d = btmpD[base+k];
      int r = atomicAdd(&cnt[d],1);
      stg[r] = btmpP[base+k];
    }
    __syncthreads();
    for (int k=t; k<nE; k+=256) sedge[base+k] = stg[k];   // coalesced writeback
  } else {
    cnt[t] = base + excl;          // fallback: direct global scatter
    __syncthreads();
    for (int k=t; k<nE; k+=256){
      int d = btmpD[base+k];
      int r = atomicAdd(&cnt[d],1);
      sedge[r] = btmpP[base+k];
    }
  }
}

// ---- transpose + bf16-convert all 18 hidden weight matrices: Wt[m][n][k] ----
__global__ __launch_bounds__(256) void k_prep_w(const float* __restrict__ wh,
    const float* __restrict__ tewl, const float* __restrict__ tewc,
    unsigned short* __restrict__ Wt){
  int gid = blockIdx.x*256+threadIdx.x;
  int m = gid>>14; int idx = gid&16383;
  int n = idx>>7, k = idx&127;
  const float* src = (m<6)? wh + (size_t)m*16384
                   : (m<12)? tewl + (size_t)(m-6)*16384
                   : tewc + (size_t)(m-12)*16384;
  Wt[gid] = f2bf(src[k*128+n]);
}

// -------- MFMA GEMM layer 0 (32-row tiles): gather emb, write xbf, compute sup --------
__global__ __launch_bounds__(256) void k_gemm_sup_emb(const int* __restrict__ verts,
    const float* __restrict__ emb, const unsigned short* __restrict__ Wt,
    unsigned short* __restrict__ Y, unsigned short* __restrict__ xout, int M){
  __shared__ unsigned short Xs[32*LSTRIDE];
  int tid = threadIdx.x;
  int row0 = blockIdx.x*32;
  #pragma unroll
  for (int it=0; it<2; it++){
    int idx = tid + it*256;
    int r = idx>>4, k8 = idx&15;
    short8 w = short8(0);
    if (row0+r < M){
      int v = verts[row0+r];
      const float4* p = (const float4*)emb + (size_t)v*32 + k8*2;
      float4 v0 = p[0], v1 = p[1];
      w[0]=(short)f2bf(v0.x); w[1]=(short)f2bf(v0.y); w[2]=(short)f2bf(v0.z); w[3]=(short)f2bf(v0.w);
      w[4]=(short)f2bf(v1.x); w[5]=(short)f2bf(v1.y); w[6]=(short)f2bf(v1.z); w[7]=(short)f2bf(v1.w);
      *(short8*)(xout + (size_t)(row0+r)*128 + k8*8) = w;
    }
    *(short8*)&Xs[r*LSTRIDE + k8*8] = w;
  }
  __syncthreads();
  int w = tid>>6, lane = tid&63, m = lane&15, q = lane>>4;
  int rw = (w&1)*16, cw = (w>>1)*64;
  f32x4 acc[4];
  #pragma unroll
  for (int nt=0;nt<4;nt++){ acc[nt][0]=0.f; acc[nt][1]=0.f; acc[nt][2]=0.f; acc[nt][3]=0.f; }
  #pragma unroll
  for (int kc=0; kc<4; kc++){
    short8 a = *(const short8*)&Xs[(rw+m)*LSTRIDE + kc*32 + 8*q];
    #pragma unroll
    for (int nt=0; nt<4; nt++){
      short8 b = *(const short8*)&Wt[(size_t)(cw+nt*16+m)*128 + kc*32 + 8*q];
      acc[nt] = __builtin_amdgcn_mfma_f32_16x16x32_bf16(a, b, acc[nt], 0,0,0);
    }
  }
  #pragma unroll
  for (int nt=0; nt<4; nt++){
    #pragma unroll
    for (int i=0;i<4;i++){
      int rr = row0 + rw + 4*q + i;
      if (rr<M) Y[(size_t)rr*128 + cw + nt*16 + m] = f2bf(acc[nt][i]);
    }
  }
}

// ------- fused gate, 64-row tiles: B-fragments reused across 2 row-tiles -------
template<int FUSE>
__global__ __launch_bounds__(256,4) void k_gemm_gate2(const unsigned short* __restrict__ H,
    const float* __restrict__ bnso,           // [scale128 | offset128], precomputed
    const unsigned short* __restrict__ Wl, const unsigned short* __restrict__ Wc,
    const unsigned short* __restrict__ Wn, const float* __restrict__ teb,
    unsigned short* __restrict__ x, unsigned short* __restrict__ supY, int M){
  __shared__ unsigned short XsX[64*LSTRIDE];
  __shared__ unsigned short XsH[64*LSTRIDE];
  int tid = threadIdx.x;
  int row0 = blockIdx.x*64;
  int k8 = tid&15;   // feature chunk, same for all 4 row-quarters
  // front-load ALL global reads before any barrier
  float4 sc0 = *(const float4*)(bnso + k8*8);
  float4 sc1 = *(const float4*)(bnso + k8*8 + 4);
  float4 of0 = *(const float4*)(bnso + 128 + k8*8);
  float4 of1 = *(const float4*)(bnso + 128 + k8*8 + 4);
  short8 xv[4], hv[4];
  #pragma unroll
  for (int it=0; it<4; it++){
    int r = (tid + it*256)>>4;
    xv[it] = short8(0); hv[it] = short8(0);
    if (row0+r < M){
      xv[it] = *(const short8*)(x + (size_t)(row0+r)*128 + k8*8);
      hv[it] = *(const short8*)(H + (size_t)(row0+r)*128 + k8*8);
    }
  }
  const float scs[8] = {sc0.x,sc0.y,sc0.z,sc0.w,sc1.x,sc1.y,sc1.z,sc1.w};
  const float ofs[8] = {of0.x,of0.y,of0.z,of0.w,of1.x,of1.y,of1.z,of1.w};
  #pragma unroll
  for (int it=0; it<4; it++){
    int r = (tid + it*256)>>4;
    *(short8*)&XsX[r*LSTRIDE + k8*8] = xv[it];
    short8 w;
    #pragma unroll
    for (int j=0;j<8;j++){
      float o = bf2f((unsigned short)hv[it][j]);
      w[j] = (short)f2bf(fmaxf(fmaf(o, scs[j], ofs[j]), 0.f));
    }
    *(short8*)&XsH[r*LSTRIDE + k8*8] = w;
  }
  __syncthreads();
  int w = tid>>6, lane = tid&63, m = lane&15, q = lane>>4;
  int rw = (w>>1)*16, cw = (w&1)*64;   // rows {rw..rw+15, rw+32..rw+47}, cols cw..cw+63
  f32x4 acc[2][4];
  #pragma unroll
  for (int rt=0;rt<2;rt++)
    #pragma unroll
    for (int nt=0;nt<4;nt++){ acc[rt][nt][0]=0.f; acc[rt][nt][1]=0.f; acc[rt][nt][2]=0.f; acc[rt][nt][3]=0.f; }
  #pragma unroll
  for (int kc=0; kc<4; kc++){
    short8 a0 = *(const short8*)&XsX[(rw+m)*LSTRIDE + kc*32 + 8*q];
    short8 a1 = *(const short8*)&XsX[(rw+32+m)*LSTRIDE + kc*32 + 8*q];
    #pragma unroll
    for (int nt=0; nt<4; nt++){
      short8 b = *(const short8*)&Wl[(size_t)(cw+nt*16+m)*128 + kc*32 + 8*q];
      acc[0][nt] = __builtin_amdgcn_mfma_f32_16x16x32_bf16(a0, b, acc[0][nt], 0,0,0);
      acc[1][nt] = __builtin_amdgcn_mfma_f32_16x16x32_bf16(a1, b, acc[1][nt], 0,0,0);
    }
  }
  #pragma unroll
  for (int kc=0; kc<4; kc++){
    short8 a0 = *(const short8*)&XsH[(rw+m)*LSTRIDE + kc*32 + 8*q];
    short8 a1 = *(const short8*)&XsH[(rw+32+m)*LSTRIDE + kc*32 + 8*q];
    #pragma unroll
    for (int nt=0; nt<4; nt++){
      short8 b = *(const short8*)&Wc[(size_t)(cw+nt*16+m)*128 + kc*32 + 8*q];
      acc[0][nt] = __builtin_amdgcn_mfma_f32_16x16x32_bf16(a0, b, acc[0][nt], 0,0,0);
      acc[1][nt] = __builtin_amdgcn_mfma_f32_16x16x32_bf16(a1, b, acc[1][nt], 0,0,0);
    }
  }
  __syncthreads();   // all MFMA A-reads done before epilogue overwrites LDS (race fix)
  // gate epilogue: each (lr,col) cell owned by exactly one thread
  #pragma unroll
  for (int rt=0; rt<2; rt++){
    #pragma unroll
    for (int nt=0; nt<4; nt++){
      int col = cw + nt*16 + m;
      float bias = teb[col];
      #pragma unroll
      for (int i=0;i<4;i++){
        int lr = rw + rt*32 + 4*q + i;
        float hvv = bf2f(XsH[lr*LSTRIDE + col]);
        float xo  = bf2f(XsX[lr*LSTRIDE + col]);
        float g = sigm(acc[rt][nt][i] + bias);
        unsigned short xnb = f2bf(g*hvv + (1.f-g)*xo);
        XsH[lr*LSTRIDE + col] = xnb;
        if (FUSE) XsX[lr*LSTRIDE + col] = xnb;
      }
    }
  }
  __syncthreads();
  // coalesced short8 writeback of x_new
  #pragma unroll
  for (int it=0; it<4; it++){
    int r = (tid + it*256)>>4;
    if (row0+r < M)
      *(short8*)(x + (size_t)(row0+r)*128 + k8*8) = *(short8*)&XsH[r*LSTRIDE + k8*8];
  }
  if (FUSE){
    #pragma unroll
    for (int rt=0;rt<2;rt++)
      #pragma unroll
      for (int nt=0;nt<4;nt++){ acc[rt][nt][0]=0.f; acc[rt][nt][1]=0.f; acc[rt][nt][2]=0.f; acc[rt][nt][3]=0.f; }
    #pragma unroll
    for (int kc=0; kc<4; kc++){
      short8 a0 = *(const short8*)&XsX[(rw+m)*LSTRIDE + kc*32 + 8*q];
      short8 a1 = *(const short8*)&XsX[(rw+32+m)*LSTRIDE + kc*32 + 8*q];
      #pragma unroll
      for (int nt=0; nt<4; nt++){
        short8 b = *(const short8*)&Wn[(size_t)(cw+nt*16+m)*128 + kc*32 + 8*q];
        acc[0][nt] = __builtin_amdgcn_mfma_f32_16x16x32_bf16(a0, b, acc[0][nt], 0,0,0);
        acc[1][nt] = __builtin_amdgcn_mfma_f32_16x16x32_bf16(a1, b, acc[1][nt], 0,0,0);
      }
    }
    #pragma unroll
    for (int rt=0; rt<2; rt++){
      #pragma unroll
      for (int nt=0; nt<4; nt++){
        #pragma unroll
        for (int i=0;i<4;i++){
          int rr = row0 + rw + rt*32 + 4*q + i;
          if (rr<M) supY[(size_t)rr*128 + cw + nt*16 + m] = f2bf(acc[rt][nt][i]);
        }
      }
    }
  }
}

// ---------------- Y[M,20] = bf16 X[M,128] @ W[128,20] (fp32 acc) ----------------
__global__ __launch_bounds__(256) void k_gemm_out(const unsigned short* __restrict__ X,
    const float* __restrict__ W, float* __restrict__ Y, int M){
  __shared__ float Ws[DIM*OUTC];
  __shared__ float Xs2[8*DIM];
  int tid=threadIdx.x;
  for (int i=tid;i<DIM*OUTC;i+=256) Ws[i]=W[i];
  int row0=blockIdx.x*8;
  if (tid<128){
    int r = tid>>4, k8 = tid&15;
    short8 v = short8(0);
    if (row0+r<M) v = *(const short8*)(X + (size_t)(row0+r)*128 + k8*8);
    #pragma unroll
    for (int j=0;j<8;j++) Xs2[r*DIM+k8*8+j] = bf2f((unsigned short)v[j]);
  }
  __syncthreads();
  int c = tid&31, rl=tid>>5;
  if (c<OUTC && row0+rl<M){
    float acc=0.f;
    #pragma unroll 8
    for (int k=0;k<DIM;k++) acc += Xs2[rl*DIM+k]*Ws[k*OUTC+c];
    Y[(size_t)(row0+rl)*OUTC+c]=acc;
  }
}

// -------- SpMM gather (8-deep unroll) + fused BN stats; last block finalizes BN --------
__global__ __launch_bounds__(256) void k_spmm128(const unsigned short* __restrict__ sup,
    const unsigned int* __restrict__ sedge, const int* __restrict__ offs,
    unsigned short* __restrict__ h, int lbase, float* __restrict__ stL,
    const float* __restrict__ gamma, const float* __restrict__ beta,
    float* __restrict__ bnso, int* __restrict__ tick){
  int nl = threadIdx.x>>5;
  int node = blockIdx.x*8 + nl;
  int fq = threadIdx.x & 31;
  int p = offs[lbase+node], end = offs[lbase+node+1];
  float4 a0 = make_float4(0.f,0.f,0.f,0.f), a1 = a0, a2 = a0, a3 = a0;
  for (; p+7<end; p+=8){
    unsigned int ev[8];
    #pragma unroll
    for (int u=0;u<8;u++) ev[u] = __builtin_nontemporal_load(sedge+p+u);
    ushort4 sv[8];
    #pragma unroll
    for (int u=0;u<8;u++) sv[u] = *(const ushort4*)(sup + (size_t)(ev[u]&0xFFFFu)*128 + fq*4);
    #pragma unroll
    for (int u=0;u<8;u++){
      float w = __half2float(__ushort_as_half((unsigned short)(ev[u]>>16)));
      float4& a = (u&3)==0? a0 : (u&3)==1? a1 : (u&3)==2? a2 : a3;
      a.x += w*bf2f(sv[u].x); a.y += w*bf2f(sv[u].y);
      a.z += w*bf2f(sv[u].z); a.w += w*bf2f(sv[u].w);
    }
  }
  for (; p+3<end; p+=4){
    unsigned int e0 = __builtin_nontemporal_load(sedge+p);
    unsigned int e1 = __builtin_nontemporal_load(sedge+p+1);
    unsigned int e2 = __builtin_nontemporal_load(sedge+p+2);
    unsigned int e3 = __builtin_nontemporal_load(sedge+p+3);
    ushort4 s0 = *(const ushort4*)(sup + (size_t)(e0&0xFFFFu)*128 + fq*4);
    ushort4 s1 = *(const ushort4*)(sup + (size_t)(e1&0xFFFFu)*128 + fq*4);
    ushort4 s2 = *(const ushort4*)(sup + (size_t)(e2&0xFFFFu)*128 + fq*4);
    ushort4 s3 = *(const ushort4*)(sup + (size_t)(e3&0xFFFFu)*128 + fq*4);
    float w0 = __half2float(__ushort_as_half((unsigned short)(e0>>16)));
    float w1 = __half2float(__ushort_as_half((unsigned short)(e1>>16)));
    float w2 = __half2float(__ushort_as_half((unsigned short)(e2>>16)));
    float w3 = __half2float(__ushort_as_half((unsigned short)(e3>>16)));
    a0.x += w0*bf2f(s0.x); a0.y += w0*bf2f(s0.y); a0.z += w0*bf2f(s0.z); a0.w += w0*bf2f(s0.w);
    a1.x += w1*bf2f(s1.x); a1.y += w1*bf2f(s1.y); a1.z += w1*bf2f(s1.z); a1.w += w1*bf2f(s1.w);
    a2.x += w2*bf2f(s2.x); a2.y += w2*bf2f(s2.y); a2.z += w2*bf2f(s2.z); a2.w += w2*bf2f(s2.w);
    a3.x += w3*bf2f(s3.x); a3.y += w3*bf2f(s3.y); a3.z += w3*bf2f(s3.z); a3.w += w3*bf2f(s3.w);
  }
  for (; p<end; p++){
    unsigned int e0 = __builtin_nontemporal_load(sedge+p);
    float w0 = __half2float(__ushort_as_half((unsigned short)(e0>>16)));
    ushort4 s0 = *(const ushort4*)(sup + (size_t)(e0&0xFFFFu)*128 + fq*4);
    a0.x += w0*bf2f(s0.x); a0.y += w0*bf2f(s0.y); a0.z += w0*bf2f(s0.z); a0.w += w0*bf2f(s0.w);
  }
  a0.x+=a1.x+a2.x+a3.x; a0.y+=a1.y+a2.y+a3.y;
  a0.z+=a1.z+a2.z+a3.z; a0.w+=a1.w+a2.w+a3.w;
  ushort4 ov;
  ov.x=f2bf(a0.x); ov.y=f2bf(a0.y); ov.z=f2bf(a0.z); ov.w=f2bf(a0.w);
  *(ushort4*)(h + (size_t)node*128 + fq*4) = ov;
  __shared__ float sP[8][132], sQ[8][132];
  int f0 = fq*4;
  sP[nl][f0+0]=a0.x; sP[nl][f0+1]=a0.y; sP[nl][f0+2]=a0.z; sP[nl][f0+3]=a0.w;
  sQ[nl][f0+0]=a0.x*a0.x; sQ[nl][f0+1]=a0.y*a0.y; sQ[nl][f0+2]=a0.z*a0.z; sQ[nl][f0+3]=a0.w*a0.w;
  __syncthreads();
  if (threadIdx.x < 128){
    int f = threadIdx.x;
    float s=0.f, sq=0.f;
    #pragma unroll
    for (int n=0;n<8;n++){ s += sP[n][f]; sq += sQ[n][f]; }
    float* base = stL + (blockIdx.x & (NREP-1))*256;
    atomicAdd(&base[f], s); atomicAdd(&base[128+f], sq);
  }
  // ---- last-block BN finalize (replaces the k_bnfin kernel bubble) ----
  __syncthreads();    // drains the atomics (vmcnt) for the whole block
  __shared__ int isLast;
  if (threadIdx.x==0){
    __threadfence();
    int tk = __hip_atomic_fetch_add(tick, 1, __ATOMIC_ACQ_REL, __HIP_MEMORY_SCOPE_AGENT);
    isLast = (tk == (NN/8)-1);
  }
  __syncthreads();
  if (isLast){
    int t = threadIdx.x;
    float acc = 0.f;
    #pragma unroll 8
    for (int g=0; g<NREP; g++)
      acc += __hip_atomic_load(&stL[g*256 + t], __ATOMIC_RELAXED, __HIP_MEMORY_SCOPE_AGENT);
    float* sh = &sP[0][0];
    sh[t] = acc;
    __syncthreads();
    if (t < 128){
      float mean = sh[t]*(1.0f/NN);
      float var  = sh[t+128]*(1.0f/NN) - mean*mean;
      float sc = rsqrtf(var+BN_EPS)*gamma[t];
      bnso[t] = sc;
      bnso[128+t] = beta[t]-mean*sc;
    }
  }
}

__global__ __launch_bounds__(256) void k_spmm_out(const float* __restrict__ sup,
    const unsigned int* __restrict__ sedge, const int* __restrict__ offs,
    float* __restrict__ h, int lbase){
  int node = blockIdx.x*8 + (threadIdx.x>>5);
  int c = threadIdx.x & 31;
  bool act = c < OUTC;
  int p = offs[lbase+node], end = offs[lbase+node+1];
  float a0=0.f,a1=0.f,a2=0.f,a3=0.f;
  for (; p+7<end; p+=8){
    unsigned int ev[8];
    #pragma unroll
    for (int u=0;u<8;u++) ev[u] = __builtin_nontemporal_load(sedge+p+u);
    float sv[8];
    #pragma unroll
    for (int u=0;u<8;u++) sv[u] = act ? sup[(size_t)(ev[u]&0xFFFFu)*OUTC+c] : 0.f;
    #pragma unroll
    for (int u=0;u<8;u++){
      float w = __half2float(__ushort_as_half((unsigned short)(ev[u]>>16)));
      if ((u&3)==0) a0 += w*sv[u];
      else if ((u&3)==1) a1 += w*sv[u];
      else if ((u&3)==2) a2 += w*sv[u];
      else a3 += w*sv[u];
    }
  }
  for (; p<end; p++){
    unsigned int e = __builtin_nontemporal_load(sedge+p);
    float w = __half2float(__ushort_as_half((unsigned short)(e>>16)));
    float sv = act ? sup[(size_t)(e&0xFFFFu)*OUTC+c] : 0.f;
    a0 += w*sv;
  }
  if (act) h[(size_t)node*OUTC+c] = a0+a1+a2+a3;
}

// ---------------- output-layer BN stats (8-way replicated) ----------------
__global__ __launch_bounds__(256) void k_bn_stats_out(const float* __restrict__ h,
    float* __restrict__ st8, int rpb){
  int f = threadIdx.x % 32;
  int g = threadIdx.x / 32;
  float s=0.f, ss=0.f;
  int r0 = blockIdx.x*rpb;
  int r1 = min(NN, r0+rpb);
  if (f < OUTC){
    for (int r=r0+g; r<r1; r+=8){ float v = h[(size_t)r*OUTC+f]; s+=v; ss+=v*v; }
  }
  __shared__ float sh[256], sh2[256];
  sh[threadIdx.x]=s; sh2[threadIdx.x]=ss; __syncthreads();
  if (threadIdx.x < 32){
    #pragma unroll
    for (int i=1;i<8;i++){ s+=sh[threadIdx.x+i*32]; ss+=sh2[threadIdx.x+i*32]; }
    if (f<OUTC){
      float* base = st8 + (blockIdx.x&7)*64;
      atomicAdd(&base[f], s); atomicAdd(&base[32+f], ss);
    }
  }
}

// ---------- fused: BN-normalize+ReLU inline + masked reduce (8-way replicated) ----------
__global__ __launch_bounds__(256) void k_reduce(const float* __restrict__ xf,
    const float* __restrict__ st8, const float* __restrict__ gamma,
    const float* __restrict__ beta, const int* __restrict__ verts,
    const float* __restrict__ mw, float* __restrict__ acc8, int rpb){
  int c = threadIdx.x & 31, g = threadIdx.x >> 5;
  float scn=0.f, offc=0.f;
  if (c<OUTC){
    float s=0.f, sq=0.f;
    #pragma unroll
    for (int i=0;i<8;i++){ s += st8[i*64+c]; sq += st8[i*64+32+c]; }
    const float invN = 1.0f/NN;
    float m = s*invN;
    float var = sq*invN - m*m;
    scn = rsqrtf(var+BN_EPS)*gamma[c];
    offc = beta[c] - m*scn;
  }
  int r0 = blockIdx.x*rpb;
  int r1 = min(NN, r0+rpb);
  float s=0.f;
  for (int r=r0+g; r<r1; r+=8){
    float m = mw[verts[r]];
    if (c<OUTC){
      float v = fmaxf(fmaf(xf[(size_t)r*OUTC+c], scn, offc), 0.f);
      s += m * v;
    }
  }
  __shared__ float sh[256];
  sh[threadIdx.x]=s; __syncthreads();
  if (threadIdx.x<32){
    #pragma unroll
    for (int i=1;i<8;i++) s += sh[threadIdx.x + i*32];
    if (c<OUTC) atomicAdd(&acc8[(blockIdx.x&7)*32 + c], s);
  }
}

__global__ void k_final(const float* __restrict__ acc8, const float* __restrict__ mb,
                        float* __restrict__ out){
  int c=threadIdx.x;
  if (c<OUTC){
    float s=0.f;
    #pragma unroll
    for (int g=0; g<8; g++) s += acc8[g*32+c];
    out[c] = sigm(s+mb[c]);
  }
}

// ---------------- host ----------------
extern "C" void kernel_launch(void* const* d_in, const int* in_sizes, int n_in,
                              void* d_out, int out_size, void* d_ws, size_t ws_size,
                              hipStream_t stream){
  const int*   verts = (const int*)d_in[0];
  const int*   ei    = (const int*)d_in[1];
  const float* ew    = (const float*)d_in[2];
  const float* emb   = (const float*)d_in[3];
  const float* wh    = (const float*)d_in[4];
  const float* w_out = (const float*)d_in[6];
  const float* bng_h = (const float*)d_in[8];
  const float* bnb_h = (const float*)d_in[9];
  const float* bng_o = (const float*)d_in[10];
  const float* bnb_o = (const float*)d_in[11];
  const float* tewl  = (const float*)d_in[12];
  const float* tewc  = (const float*)d_in[13];
  const float* teb   = (const float*)d_in[14];
  const float* maskw = (const float*)d_in[15];
  const float* maskb = (const float*)d_in[16];
  float* out = (float*)d_out;

  char* ws = (char*)d_ws;
  size_t off=0;
  auto alloc=[&](size_t bytes)->char*{ char* p = ws+off; off += (bytes+255)&~(size_t)255; return p; };
  unsigned int* sedge = (unsigned int*)alloc(sizeof(int)*LE);   // 22.4 MB
  int*   offs   = (int*)  alloc(sizeof(int)*(LN+1));            // 1.4 MB
  int*   Gm     = (int*)  alloc(sizeof(int)*LL*NBLK*GMS);       // 1.1 MB
  int*   S      = (int*)  alloc(sizeof(int)*(SCN+1));           // 1.1 MB
  int*   bsums  = (int*)  alloc(sizeof(int)*1024);
  unsigned short* xbf   = (unsigned short*)alloc(sizeof(short)*NN*DIM); // 12.8 MB
  unsigned short* supbf = (unsigned short*)alloc(sizeof(short)*NN*DIM); // 12.8 MB
  unsigned short* hbf   = (unsigned short*)alloc(sizeof(short)*NN*DIM); // 12.8 MB
  float* buf20  = (float*)alloc(sizeof(float)*NN*OUTC);         // 4 MB
  unsigned short* Wt = (unsigned short*)alloc(sizeof(short)*18*DIM*DIM);
  const int STATSZ = 6*NREP*256 + 8*64 + 8*32 + 256 + 8;
  float* stats  = (float*)alloc(sizeof(float)*STATSZ);
  float* ostat8 = stats + 6*NREP*256;  // [8][64]
  float* racc8  = ostat8 + 8*64;       // [8][32]
  float* bnso   = racc8 + 8*32;        // [scale128 | offset128]
  int*   ticks  = (int*)(bnso + 256);  // [6] per-layer completion tickets
  unsigned int*  btmpP = (unsigned int*)xbf;
  unsigned char* btmpD = (unsigned char*)hbf;

  // --- preprocessing: LDS-atomic counting sort (histogram shared bh->bscatter) ---
  hipMemsetAsync(stats, 0, sizeof(float)*STATSZ, stream);
  k_prep_w<<<1152,256,0,stream>>>(wh, tewl, tewc, Wt);
  k_bh<<<LL*NBLK,256,0,stream>>>(ei, Gm);
  int nsb = (SCN+4095)/4096;  // 68
  k_scan1p<<<nsb,256,0,stream>>>(Gm, S, bsums);
  k_scan2<<<1,1024,0,stream>>>(bsums, nsb);
  k_scan3<<<(SCN+255)/256,256,0,stream>>>(S, bsums);
  k_bscatter<<<LL*NBLK,256,0,stream>>>(ei, ew, S, Gm, btmpP, btmpD);
  k_fsort<<<LL*NBUK,256,0,stream>>>(btmpP, btmpD, S, sedge, offs);

  // --- 6 hidden layers; sup for layer i+1 computed inside gate2 of layer i ---
  k_gemm_sup_emb<<<(NN+31)/32,256,0,stream>>>(verts, emb, Wt, supbf, xbf, NN);
  for (int i=0;i<6;i++){
    int j = (i==0)?5:(i-1);
    float* stL = stats + i*NREP*256;
    k_spmm128<<<NN/8,256,0,stream>>>(supbf, sedge, offs, hbf, i*NN, stL,
        bng_h+(size_t)i*DIM, bnb_h+(size_t)i*DIM, bnso, ticks+i);
    if (i<5)
      k_gemm_gate2<1><<<(NN+63)/64,256,0,stream>>>(hbf, bnso,
          Wt + (size_t)(6+j)*DIM*DIM, Wt + (size_t)(12+j)*DIM*DIM,
          Wt + (size_t)(i+1)*DIM*DIM, teb + (size_t)j*DIM, xbf, supbf, NN);
    else
      k_gemm_gate2<0><<<(NN+63)/64,256,0,stream>>>(hbf, bnso,
          Wt + (size_t)(6+j)*DIM*DIM, Wt + (size_t)(12+j)*DIM*DIM,
          Wt, teb + (size_t)j*DIM, xbf, supbf, NN);
  }

  // --- output layer (fp32 accumulate) ---
  k_gemm_out<<<(NN+7)/8,256,0,stream>>>(xbf, w_out, buf20, NN);
  k_spmm_out<<<NN/8,256,0,stream>>>(buf20, sedge, offs, (float*)hbf, 6*NN);
  float* bufO = (float*)hbf;
  k_bn_stats_out<<<512,256,0,stream>>>(bufO, ostat8, 98);
  k_reduce<<<512,256,0,stream>>>(bufO, ostat8, bng_o, bnb_o, verts, maskw, racc8, 98);
  k_final<<<1,64,0,stream>>>(racc8, maskb, out);
}

// Round 4
// 742.685 us; speedup vs baseline: 3.6743x; 3.6743x over previous
//
#include <hip/hip_runtime.h>
#include <hip/hip_fp16.h>

#define NN 50000
#define EE 800000
#define DIM 128
#define OUTC 20
#define LL 7
#define LE (LL*EE)
#define LN (LL*NN)
#define BN_EPS 1e-5f
#define LSTRIDE 136     // bf16 elems per LDS row
#define NREP 64         // BN stat replicas
#define NBUK 196        // coarse buckets of 256 dsts per layer
#define GMS  200        // padded Gm stride
#define NBLK 200        // edge-blocks per layer (EE/NBLK = 4000)
#define CH   4000
#define SCN  (LL*NBUK*NBLK)   // 274400 scan entries
#define FSCAP 4864      // fsort LDS staging capacity

typedef __attribute__((ext_vector_type(8))) short short8;
typedef __attribute__((ext_vector_type(4))) float f32x4;

static __device__ __forceinline__ float sigm(float z){ return 1.0f/(1.0f+expf(-z)); }
static __device__ __forceinline__ unsigned short f2bf(float f){
  unsigned int u = __float_as_uint(f);
  u += 0x7FFF + ((u>>16)&1);            // RNE
  return (unsigned short)(u>>16);
}
static __device__ __forceinline__ float bf2f(unsigned short s){
  return __uint_as_float(((unsigned int)s)<<16);
}

// ======== preprocessing: counting sort, all atomics in LDS, pure streaming ========

__global__ __launch_bounds__(256) void k_bh(const int* __restrict__ ei,
    int* __restrict__ Gm){
  int l = blockIdx.x / NBLK, b = blockIdx.x - l*NBLK;
  int t = threadIdx.x;
  __shared__ int h[NBUK];
  if (t<NBUK) h[t]=0;
  const int* dsts = ei + (size_t)(2*l+1)*EE + b*CH;
  int dv[16];
  #pragma unroll
  for (int i=0;i<16;i++){
    int k = t + i*256;
    if (k<CH) dv[i] = __builtin_nontemporal_load(dsts+k);
  }
  __syncthreads();
  #pragma unroll
  for (int i=0;i<16;i++){
    int k = t + i*256;
    if (k<CH) atomicAdd(&h[dv[i]>>8], 1);
  }
  __syncthreads();
  int* g = Gm + (size_t)(l*NBLK+b)*GMS;
  if (t<NBUK) g[t]=h[t];
}

__global__ __launch_bounds__(256) void k_scan1p(const int* __restrict__ Gm,
    int* __restrict__ part, int* __restrict__ bsums){
  __shared__ int s[256];
  int t = threadIdx.x;
  int base = blockIdx.x*4096 + t*16;
  int v[16]; int sum = 0;
  #pragma unroll
  for (int i=0;i<16;i++){
    int idx = base+i; int val = 0;
    if (idx < SCN){
      int l = idx/(NBUK*NBLK);
      int r = idx - l*(NBUK*NBLK);
      int buk = r/NBLK, b = r - buk*NBLK;
      val = Gm[(size_t)(l*NBLK+b)*GMS + buk];
    }
    v[i]=val; sum+=val;
  }
  s[t]=sum; __syncthreads();
  for (int off=1; off<256; off<<=1){
    int x = (t>=off)? s[t-off] : 0;
    __syncthreads(); s[t]+=x; __syncthreads();
  }
  if (t==255) bsums[blockIdx.x] = s[255];
  int run = s[t]-sum;
  #pragma unroll
  for (int i=0;i<16;i++){ if (base+i<SCN) part[base+i]=run; run += v[i]; }
}

__global__ __launch_bounds__(1024) void k_scan2(int* bsums, int nb){
  __shared__ int s[1024];
  int t=threadIdx.x;
  int v = (t<nb)? bsums[t]:0;
  s[t]=v; __syncthreads();
  for (int off=1; off<1024; off<<=1){
    int x=(t>=off)? s[t-off]:0; __syncthreads(); s[t]+=x; __syncthreads();
  }
  if (t<nb) bsums[t] = s[t]-v;
}

__global__ void k_scan3(int* __restrict__ S, const int* __restrict__ bsums){
  int gid = blockIdx.x*256+threadIdx.x;
  if (gid < SCN) S[gid] += bsums[gid>>12];
  if (gid==0) S[SCN]=LE;
}

// P3: LDS counting-sort by bucket with FINAL payload stored at placement.
__global__ __launch_bounds__(256) void k_bscatter(const int* __restrict__ ei,
    const float* __restrict__ ew, const int* __restrict__ S,
    const int* __restrict__ Gm,
    unsigned int* __restrict__ btmpP, unsigned char* __restrict__ btmpD){
  int l = blockIdx.x / NBLK, b = blockIdx.x - l*NBLK;
  int t = threadIdx.x;
  __shared__ int bstart[NBUK], cur[NBUK], runb[NBUK];
  __shared__ int ps[256];
  __shared__ unsigned int  ebP[CH];     // 16 KB: src16|halfw16
  __shared__ unsigned short ebM[CH];    // 8 KB:  dlow8|buk8
  const int* srcs = ei + (size_t)(2*l)*EE + b*CH;
  const int* dsts = ei + (size_t)(2*l+1)*EE + b*CH;
  const float* wsrc = ew + (size_t)l*EE + b*CH;
  int sv[16], dv[16]; float wv[16];
  #pragma unroll
  for (int i=0;i<16;i++){
    int k = t + i*256;
    if (k<CH){
      sv[i] = __builtin_nontemporal_load(srcs+k);
      dv[i] = __builtin_nontemporal_load(dsts+k);
      wv[i] = __builtin_nontemporal_load(wsrc+k);
    }
  }
  int v = (t<NBUK)? Gm[(size_t)(l*NBLK+b)*GMS + t] : 0;
  ps[t]=v; __syncthreads();
  for (int o=1;o<256;o<<=1){ int x=(t>=o)?ps[t-o]:0; __syncthreads(); ps[t]+=x; __syncthreads(); }
  if (t<NBUK){ bstart[t]=ps[t]-v; cur[t]=ps[t]-v; runb[t] = S[(size_t)(l*NBUK+t)*NBLK + b]; }
  __syncthreads();
  #pragma unroll
  for (int i=0;i<16;i++){
    int k = t + i*256;
    if (k<CH){
      int buk = dv[i]>>8;
      int pos = atomicAdd(&cur[buk],1);
      unsigned short hw = __half_as_ushort(__float2half(wv[i]));
      ebP[pos] = (unsigned)sv[i] | ((unsigned)hw<<16);
      ebM[pos] = (unsigned short)((dv[i]&255) | (buk<<8));
    }
  }
  __syncthreads();
  for (int k=t;k<CH;k+=256){
    unsigned short m = ebM[k];
    int buk = m>>8;
    int gp = runb[buk] + (k - bstart[buk]);
    btmpP[gp] = ebP[k];
    btmpD[gp] = (unsigned char)(m&255);
  }
}

// P4: per-bucket count+scan; scatter staged through LDS for coalesced writeback.
__global__ __launch_bounds__(256) void k_fsort(const unsigned int* __restrict__ btmpP,
    const unsigned char* __restrict__ btmpD, const int* __restrict__ S,
    unsigned int* __restrict__ sedge, int* __restrict__ offs){
  int lbuk = blockIdx.x;
  int l = lbuk/NBUK, bl = lbuk - l*NBUK;
  int t = threadIdx.x;
  int base = S[(size_t)lbuk*NBLK];
  int end  = S[(size_t)(lbuk+1)*NBLK];
  int nE = end - base;
  __shared__ int cnt[256], sc[256];
  __shared__ unsigned int stg[FSCAP];
  cnt[t]=0;
  __syncthreads();
  for (int k=t; k<nE; k+=256) atomicAdd(&cnt[btmpD[base+k]], 1);
  __syncthreads();
  int c = cnt[t];
  sc[t]=c;
  __syncthreads();
  for (int o=1;o<256;o<<=1){
    int v = (t>=o)? sc[t-o]:0;
    __syncthreads();
    sc[t]+=v;
    __syncthreads();
  }
  int excl = sc[t]-c;
  {
    int node = bl*256+t;
    if (node<NN) offs[(size_t)l*NN+node] = base + excl;
  }
  if (lbuk==0 && t==255) offs[LN]=LE;
  if (nE <= FSCAP){
    cnt[t] = excl;                 // LDS-relative running cursor
    __syncthreads();
    for (int k=t; k<nE; k+=256){
      int d = btmpD[base+k];
      int r = atomicAdd(&cnt[d],1);
      stg[r] = btmpP[base+k];
    }
    __syncthreads();
    for (int k=t; k<nE; k+=256) sedge[base+k] = stg[k];   // coalesced writeback
  } else {
    cnt[t] = base + excl;          // fallback: direct global scatter
    __syncthreads();
    for (int k=t; k<nE; k+=256){
      int d = btmpD[base+k];
      int r = atomicAdd(&cnt[d],1);
      sedge[r] = btmpP[base+k];
    }
  }
}

// ---- transpose + bf16-convert all 18 hidden weight matrices: Wt[m][n][k] ----
__global__ __launch_bounds__(256) void k_prep_w(const float* __restrict__ wh,
    const float* __restrict__ tewl, const float* __restrict__ tewc,
    unsigned short* __restrict__ Wt){
  int gid = blockIdx.x*256+threadIdx.x;
  int m = gid>>14; int idx = gid&16383;
  int n = idx>>7, k = idx&127;
  const float* src = (m<6)? wh + (size_t)m*16384
                   : (m<12)? tewl + (size_t)(m-6)*16384
                   : tewc + (size_t)(m-12)*16384;
  Wt[gid] = f2bf(src[k*128+n]);
}

// ---- BN finalize: reduce NREP replicas once per layer -> scale[128] | offset[128] ----
__global__ __launch_bounds__(256) void k_bnfin(const float* __restrict__ stL,
    const float* __restrict__ gamma, const float* __restrict__ beta,
    float* __restrict__ bnso){
  __shared__ float sh[256];
  int t = threadIdx.x;
  float acc = 0.f;
  #pragma unroll 8
  for (int g=0; g<NREP; g++) acc += stL[g*256 + t];
  sh[t] = acc;
  __syncthreads();
  if (t < 128){
    float mean = sh[t]*(1.0f/NN);
    float var  = sh[t+128]*(1.0f/NN) - mean*mean;
    float sc = rsqrtf(var+BN_EPS)*gamma[t];
    bnso[t] = sc;
    bnso[128+t] = beta[t]-mean*sc;
  }
}

// -------- MFMA GEMM layer 0 (32-row tiles): gather emb, write xbf, compute sup --------
__global__ __launch_bounds__(256) void k_gemm_sup_emb(const int* __restrict__ verts,
    const float* __restrict__ emb, const unsigned short* __restrict__ Wt,
    unsigned short* __restrict__ Y, unsigned short* __restrict__ xout, int M){
  __shared__ unsigned short Xs[32*LSTRIDE];
  int tid = threadIdx.x;
  int row0 = blockIdx.x*32;
  #pragma unroll
  for (int it=0; it<2; it++){
    int idx = tid + it*256;
    int r = idx>>4, k8 = idx&15;
    short8 w = short8(0);
    if (row0+r < M){
      int v = verts[row0+r];
      const float4* p = (const float4*)emb + (size_t)v*32 + k8*2;
      float4 v0 = p[0], v1 = p[1];
      w[0]=(short)f2bf(v0.x); w[1]=(short)f2bf(v0.y); w[2]=(short)f2bf(v0.z); w[3]=(short)f2bf(v0.w);
      w[4]=(short)f2bf(v1.x); w[5]=(short)f2bf(v1.y); w[6]=(short)f2bf(v1.z); w[7]=(short)f2bf(v1.w);
      *(short8*)(xout + (size_t)(row0+r)*128 + k8*8) = w;
    }
    *(short8*)&Xs[r*LSTRIDE + k8*8] = w;
  }
  __syncthreads();
  int w = tid>>6, lane = tid&63, m = lane&15, q = lane>>4;
  int rw = (w&1)*16, cw = (w>>1)*64;
  f32x4 acc[4];
  #pragma unroll
  for (int nt=0;nt<4;nt++){ acc[nt][0]=0.f; acc[nt][1]=0.f; acc[nt][2]=0.f; acc[nt][3]=0.f; }
  #pragma unroll
  for (int kc=0; kc<4; kc++){
    short8 a = *(const short8*)&Xs[(rw+m)*LSTRIDE + kc*32 + 8*q];
    #pragma unroll
    for (int nt=0; nt<4; nt++){
      short8 b = *(const short8*)&Wt[(size_t)(cw+nt*16+m)*128 + kc*32 + 8*q];
      acc[nt] = __builtin_amdgcn_mfma_f32_16x16x32_bf16(a, b, acc[nt], 0,0,0);
    }
  }
  #pragma unroll
  for (int nt=0; nt<4; nt++){
    #pragma unroll
    for (int i=0;i<4;i++){
      int rr = row0 + rw + 4*q + i;
      if (rr<M) Y[(size_t)rr*128 + cw + nt*16 + m] = f2bf(acc[nt][i]);
    }
  }
}

// ------- fused gate, 64-row tiles: B-fragments reused across 2 row-tiles -------
template<int FUSE>
__global__ __launch_bounds__(256,4) void k_gemm_gate2(const unsigned short* __restrict__ H,
    const float* __restrict__ bnso,           // [scale128 | offset128], precomputed
    const unsigned short* __restrict__ Wl, const unsigned short* __restrict__ Wc,
    const unsigned short* __restrict__ Wn, const float* __restrict__ teb,
    unsigned short* __restrict__ x, unsigned short* __restrict__ supY, int M){
  __shared__ unsigned short XsX[64*LSTRIDE];
  __shared__ unsigned short XsH[64*LSTRIDE];
  int tid = threadIdx.x;
  int row0 = blockIdx.x*64;
  int k8 = tid&15;   // feature chunk, same for all 4 row-quarters
  // front-load ALL global reads before any barrier
  float4 sc0 = *(const float4*)(bnso + k8*8);
  float4 sc1 = *(const float4*)(bnso + k8*8 + 4);
  float4 of0 = *(const float4*)(bnso + 128 + k8*8);
  float4 of1 = *(const float4*)(bnso + 128 + k8*8 + 4);
  short8 xv[4], hv[4];
  #pragma unroll
  for (int it=0; it<4; it++){
    int r = (tid + it*256)>>4;
    xv[it] = short8(0); hv[it] = short8(0);
    if (row0+r < M){
      xv[it] = *(const short8*)(x + (size_t)(row0+r)*128 + k8*8);
      hv[it] = *(const short8*)(H + (size_t)(row0+r)*128 + k8*8);
    }
  }
  const float scs[8] = {sc0.x,sc0.y,sc0.z,sc0.w,sc1.x,sc1.y,sc1.z,sc1.w};
  const float ofs[8] = {of0.x,of0.y,of0.z,of0.w,of1.x,of1.y,of1.z,of1.w};
  #pragma unroll
  for (int it=0; it<4; it++){
    int r = (tid + it*256)>>4;
    *(short8*)&XsX[r*LSTRIDE + k8*8] = xv[it];
    short8 w;
    #pragma unroll
    for (int j=0;j<8;j++){
      float o = bf2f((unsigned short)hv[it][j]);
      w[j] = (short)f2bf(fmaxf(fmaf(o, scs[j], ofs[j]), 0.f));
    }
    *(short8*)&XsH[r*LSTRIDE + k8*8] = w;
  }
  __syncthreads();
  int w = tid>>6, lane = tid&63, m = lane&15, q = lane>>4;
  int rw = (w>>1)*16, cw = (w&1)*64;   // rows {rw..rw+15, rw+32..rw+47}, cols cw..cw+63
  f32x4 acc[2][4];
  #pragma unroll
  for (int rt=0;rt<2;rt++)
    #pragma unroll
    for (int nt=0;nt<4;nt++){ acc[rt][nt][0]=0.f; acc[rt][nt][1]=0.f; acc[rt][nt][2]=0.f; acc[rt][nt][3]=0.f; }
  #pragma unroll
  for (int kc=0; kc<4; kc++){
    short8 a0 = *(const short8*)&XsX[(rw+m)*LSTRIDE + kc*32 + 8*q];
    short8 a1 = *(const short8*)&XsX[(rw+32+m)*LSTRIDE + kc*32 + 8*q];
    #pragma unroll
    for (int nt=0; nt<4; nt++){
      short8 b = *(const short8*)&Wl[(size_t)(cw+nt*16+m)*128 + kc*32 + 8*q];
      acc[0][nt] = __builtin_amdgcn_mfma_f32_16x16x32_bf16(a0, b, acc[0][nt], 0,0,0);
      acc[1][nt] = __builtin_amdgcn_mfma_f32_16x16x32_bf16(a1, b, acc[1][nt], 0,0,0);
    }
  }
  #pragma unroll
  for (int kc=0; kc<4; kc++){
    short8 a0 = *(const short8*)&XsH[(rw+m)*LSTRIDE + kc*32 + 8*q];
    short8 a1 = *(const short8*)&XsH[(rw+32+m)*LSTRIDE + kc*32 + 8*q];
    #pragma unroll
    for (int nt=0; nt<4; nt++){
      short8 b = *(const short8*)&Wc[(size_t)(cw+nt*16+m)*128 + kc*32 + 8*q];
      acc[0][nt] = __builtin_amdgcn_mfma_f32_16x16x32_bf16(a0, b, acc[0][nt], 0,0,0);
      acc[1][nt] = __builtin_amdgcn_mfma_f32_16x16x32_bf16(a1, b, acc[1][nt], 0,0,0);
    }
  }
  __syncthreads();   // all MFMA A-reads done before epilogue overwrites LDS (race fix)
  // gate epilogue: each (lr,col) cell owned by exactly one thread
  #pragma unroll
  for (int rt=0; rt<2; rt++){
    #pragma unroll
    for (int nt=0; nt<4; nt++){
      int col = cw + nt*16 + m;
      float bias = teb[col];
      #pragma unroll
      for (int i=0;i<4;i++){
        int lr = rw + rt*32 + 4*q + i;
        float hvv = bf2f(XsH[lr*LSTRIDE + col]);
        float xo  = bf2f(XsX[lr*LSTRIDE + col]);
        float g = sigm(acc[rt][nt][i] + bias);
        unsigned short xnb = f2bf(g*hvv + (1.f-g)*xo);
        XsH[lr*LSTRIDE + col] = xnb;
        if (FUSE) XsX[lr*LSTRIDE + col] = xnb;
      }
    }
  }
  __syncthreads();
  // coalesced short8 writeback of x_new
  #pragma unroll
  for (int it=0; it<4; it++){
    int r = (tid + it*256)>>4;
    if (row0+r < M)
      *(short8*)(x + (size_t)(row0+r)*128 + k8*8) = *(short8*)&XsH[r*LSTRIDE + k8*8];
  }
  if (FUSE){
    #pragma unroll
    for (int rt=0;rt<2;rt++)
      #pragma unroll
      for (int nt=0;nt<4;nt++){ acc[rt][nt][0]=0.f; acc[rt][nt][1]=0.f; acc[rt][nt][2]=0.f; acc[rt][nt][3]=0.f; }
    #pragma unroll
    for (int kc=0; kc<4; kc++){
      short8 a0 = *(const short8*)&XsX[(rw+m)*LSTRIDE + kc*32 + 8*q];
      short8 a1 = *(const short8*)&XsX[(rw+32+m)*LSTRIDE + kc*32 + 8*q];
      #pragma unroll
      for (int nt=0; nt<4; nt++){
        short8 b = *(const short8*)&Wn[(size_t)(cw+nt*16+m)*128 + kc*32 + 8*q];
        acc[0][nt] = __builtin_amdgcn_mfma_f32_16x16x32_bf16(a0, b, acc[0][nt], 0,0,0);
        acc[1][nt] = __builtin_amdgcn_mfma_f32_16x16x32_bf16(a1, b, acc[1][nt], 0,0,0);
      }
    }
    #pragma unroll
    for (int rt=0; rt<2; rt++){
      #pragma unroll
      for (int nt=0; nt<4; nt++){
        #pragma unroll
        for (int i=0;i<4;i++){
          int rr = row0 + rw + rt*32 + 4*q + i;
          if (rr<M) supY[(size_t)rr*128 + cw + nt*16 + m] = f2bf(acc[rt][nt][i]);
        }
      }
    }
  }
}

// ---------------- Y[M,20] = bf16 X[M,128] @ W[128,20] (fp32 acc) ----------------
__global__ __launch_bounds__(256) void k_gemm_out(const unsigned short* __restrict__ X,
    const float* __restrict__ W, float* __restrict__ Y, int M){
  __shared__ float Ws[DIM*OUTC];
  __shared__ float Xs2[8*DIM];
  int tid=threadIdx.x;
  for (int i=tid;i<DIM*OUTC;i+=256) Ws[i]=W[i];
  int row0=blockIdx.x*8;
  if (tid<128){
    int r = tid>>4, k8 = tid&15;
    short8 v = short8(0);
    if (row0+r<M) v = *(const short8*)(X + (size_t)(row0+r)*128 + k8*8);
    #pragma unroll
    for (int j=0;j<8;j++) Xs2[r*DIM+k8*8+j] = bf2f((unsigned short)v[j]);
  }
  __syncthreads();
  int c = tid&31, rl=tid>>5;
  if (c<OUTC && row0+rl<M){
    float acc=0.f;
    #pragma unroll 8
    for (int k=0;k<DIM;k++) acc += Xs2[rl*DIM+k]*Ws[k*OUTC+c];
    Y[(size_t)(row0+rl)*OUTC+c]=acc;
  }
}

// -------- SpMM gather (contiguous per-node edges, 8-deep unroll) + fused BN stats --------
// (exact round-2 body: do NOT add tail code here — it wrecks regalloc of the gather loop)
__global__ __launch_bounds__(256) void k_spmm128(const unsigned short* __restrict__ sup,
    const unsigned int* __restrict__ sedge, const int* __restrict__ offs,
    unsigned short* __restrict__ h, int lbase, float* __restrict__ stL){
  int nl = threadIdx.x>>5;
  int node = blockIdx.x*8 + nl;
  int fq = threadIdx.x & 31;
  int p = offs[lbase+node], end = offs[lbase+node+1];
  float4 a0 = make_float4(0.f,0.f,0.f,0.f), a1 = a0, a2 = a0, a3 = a0;
  for (; p+7<end; p+=8){
    unsigned int ev[8];
    #pragma unroll
    for (int u=0;u<8;u++) ev[u] = __builtin_nontemporal_load(sedge+p+u);
    ushort4 sv[8];
    #pragma unroll
    for (int u=0;u<8;u++) sv[u] = *(const ushort4*)(sup + (size_t)(ev[u]&0xFFFFu)*128 + fq*4);
    #pragma unroll
    for (int u=0;u<8;u++){
      float w = __half2float(__ushort_as_half((unsigned short)(ev[u]>>16)));
      float4& a = (u&3)==0? a0 : (u&3)==1? a1 : (u&3)==2? a2 : a3;
      a.x += w*bf2f(sv[u].x); a.y += w*bf2f(sv[u].y);
      a.z += w*bf2f(sv[u].z); a.w += w*bf2f(sv[u].w);
    }
  }
  for (; p+3<end; p+=4){
    unsigned int e0 = __builtin_nontemporal_load(sedge+p);
    unsigned int e1 = __builtin_nontemporal_load(sedge+p+1);
    unsigned int e2 = __builtin_nontemporal_load(sedge+p+2);
    unsigned int e3 = __builtin_nontemporal_load(sedge+p+3);
    ushort4 s0 = *(const ushort4*)(sup + (size_t)(e0&0xFFFFu)*128 + fq*4);
    ushort4 s1 = *(const ushort4*)(sup + (size_t)(e1&0xFFFFu)*128 + fq*4);
    ushort4 s2 = *(const ushort4*)(sup + (size_t)(e2&0xFFFFu)*128 + fq*4);
    ushort4 s3 = *(const ushort4*)(sup + (size_t)(e3&0xFFFFu)*128 + fq*4);
    float w0 = __half2float(__ushort_as_half((unsigned short)(e0>>16)));
    float w1 = __half2float(__ushort_as_half((unsigned short)(e1>>16)));
    float w2 = __half2float(__ushort_as_half((unsigned short)(e2>>16)));
    float w3 = __half2float(__ushort_as_half((unsigned short)(e3>>16)));
    a0.x += w0*bf2f(s0.x); a0.y += w0*bf2f(s0.y); a0.z += w0*bf2f(s0.z); a0.w += w0*bf2f(s0.w);
    a1.x += w1*bf2f(s1.x); a1.y += w1*bf2f(s1.y); a1.z += w1*bf2f(s1.z); a1.w += w1*bf2f(s1.w);
    a2.x += w2*bf2f(s2.x); a2.y += w2*bf2f(s2.y); a2.z += w2*bf2f(s2.z); a2.w += w2*bf2f(s2.w);
    a3.x += w3*bf2f(s3.x); a3.y += w3*bf2f(s3.y); a3.z += w3*bf2f(s3.z); a3.w += w3*bf2f(s3.w);
  }
  for (; p<end; p++){
    unsigned int e0 = __builtin_nontemporal_load(sedge+p);
    float w0 = __half2float(__ushort_as_half((unsigned short)(e0>>16)));
    ushort4 s0 = *(const ushort4*)(sup + (size_t)(e0&0xFFFFu)*128 + fq*4);
    a0.x += w0*bf2f(s0.x); a0.y += w0*bf2f(s0.y); a0.z += w0*bf2f(s0.z); a0.w += w0*bf2f(s0.w);
  }
  a0.x+=a1.x+a2.x+a3.x; a0.y+=a1.y+a2.y+a3.y;
  a0.z+=a1.z+a2.z+a3.z; a0.w+=a1.w+a2.w+a3.w;
  ushort4 ov;
  ov.x=f2bf(a0.x); ov.y=f2bf(a0.y); ov.z=f2bf(a0.z); ov.w=f2bf(a0.w);
  *(ushort4*)(h + (size_t)node*128 + fq*4) = ov;
  __shared__ float sP[8][132], sQ[8][132];
  int f0 = fq*4;
  sP[nl][f0+0]=a0.x; sP[nl][f0+1]=a0.y; sP[nl][f0+2]=a0.z; sP[nl][f0+3]=a0.w;
  sQ[nl][f0+0]=a0.x*a0.x; sQ[nl][f0+1]=a0.y*a0.y; sQ[nl][f0+2]=a0.z*a0.z; sQ[nl][f0+3]=a0.w*a0.w;
  __syncthreads();
  if (threadIdx.x < 128){
    int f = threadIdx.x;
    float s=0.f, sq=0.f;
    #pragma unroll
    for (int n=0;n<8;n++){ s += sP[n][f]; sq += sQ[n][f]; }
    float* base = stL + (blockIdx.x & (NREP-1))*256;
    atomicAdd(&base[f], s); atomicAdd(&base[128+f], sq);
  }
}

__global__ __launch_bounds__(256) void k_spmm_out(const float* __restrict__ sup,
    const unsigned int* __restrict__ sedge, const int* __restrict__ offs,
    float* __restrict__ h, int lbase){
  int node = blockIdx.x*8 + (threadIdx.x>>5);
  int c = threadIdx.x & 31;
  bool act = c < OUTC;
  int p = offs[lbase+node], end = offs[lbase+node+1];
  float a0=0.f,a1=0.f,a2=0.f,a3=0.f;
  for (; p+7<end; p+=8){
    unsigned int ev[8];
    #pragma unroll
    for (int u=0;u<8;u++) ev[u] = __builtin_nontemporal_load(sedge+p+u);
    float sv[8];
    #pragma unroll
    for (int u=0;u<8;u++) sv[u] = act ? sup[(size_t)(ev[u]&0xFFFFu)*OUTC+c] : 0.f;
    #pragma unroll
    for (int u=0;u<8;u++){
      float w = __half2float(__ushort_as_half((unsigned short)(ev[u]>>16)));
      if ((u&3)==0) a0 += w*sv[u];
      else if ((u&3)==1) a1 += w*sv[u];
      else if ((u&3)==2) a2 += w*sv[u];
      else a3 += w*sv[u];
    }
  }
  for (; p<end; p++){
    unsigned int e = __builtin_nontemporal_load(sedge+p);
    float w = __half2float(__ushort_as_half((unsigned short)(e>>16)));
    float sv = act ? sup[(size_t)(e&0xFFFFu)*OUTC+c] : 0.f;
    a0 += w*sv;
  }
  if (act) h[(size_t)node*OUTC+c] = a0+a1+a2+a3;
}

// ---------------- output-layer BN stats (8-way replicated) ----------------
__global__ __launch_bounds__(256) void k_bn_stats_out(const float* __restrict__ h,
    float* __restrict__ st8, int rpb){
  int f = threadIdx.x % 32;
  int g = threadIdx.x / 32;
  float s=0.f, ss=0.f;
  int r0 = blockIdx.x*rpb;
  int r1 = min(NN, r0+rpb);
  if (f < OUTC){
    for (int r=r0+g; r<r1; r+=8){ float v = h[(size_t)r*OUTC+f]; s+=v; ss+=v*v; }
  }
  __shared__ float sh[256], sh2[256];
  sh[threadIdx.x]=s; sh2[threadIdx.x]=ss; __syncthreads();
  if (threadIdx.x < 32){
    #pragma unroll
    for (int i=1;i<8;i++){ s+=sh[threadIdx.x+i*32]; ss+=sh2[threadIdx.x+i*32]; }
    if (f<OUTC){
      float* base = st8 + (blockIdx.x&7)*64;
      atomicAdd(&base[f], s); atomicAdd(&base[32+f], ss);
    }
  }
}

// ---------- fused: BN-normalize+ReLU inline + masked reduce (8-way replicated) ----------
__global__ __launch_bounds__(256) void k_reduce(const float* __restrict__ xf,
    const float* __restrict__ st8, const float* __restrict__ gamma,
    const float* __restrict__ beta, const int* __restrict__ verts,
    const float* __restrict__ mw, float* __restrict__ acc8, int rpb){
  int c = threadIdx.x & 31, g = threadIdx.x >> 5;
  float scn=0.f, offc=0.f;
  if (c<OUTC){
    float s=0.f, sq=0.f;
    #pragma unroll
    for (int i=0;i<8;i++){ s += st8[i*64+c]; sq += st8[i*64+32+c]; }
    const float invN = 1.0f/NN;
    float m = s*invN;
    float var = sq*invN - m*m;
    scn = rsqrtf(var+BN_EPS)*gamma[c];
    offc = beta[c] - m*scn;
  }
  int r0 = blockIdx.x*rpb;
  int r1 = min(NN, r0+rpb);
  float s=0.f;
  for (int r=r0+g; r<r1; r+=8){
    float m = mw[verts[r]];
    if (c<OUTC){
      float v = fmaxf(fmaf(xf[(size_t)r*OUTC+c], scn, offc), 0.f);
      s += m * v;
    }
  }
  __shared__ float sh[256];
  sh[threadIdx.x]=s; __syncthreads();
  if (threadIdx.x<32){
    #pragma unroll
    for (int i=1;i<8;i++) s += sh[threadIdx.x + i*32];
    if (c<OUTC) atomicAdd(&acc8[(blockIdx.x&7)*32 + c], s);
  }
}

__global__ void k_final(const float* __restrict__ acc8, const float* __restrict__ mb,
                        float* __restrict__ out){
  int c=threadIdx.x;
  if (c<OUTC){
    float s=0.f;
    #pragma unroll
    for (int g=0; g<8; g++) s += acc8[g*32+c];
    out[c] = sigm(s+mb[c]);
  }
}

// ---------------- host ----------------
extern "C" void kernel_launch(void* const* d_in, const int* in_sizes, int n_in,
                              void* d_out, int out_size, void* d_ws, size_t ws_size,
                              hipStream_t stream){
  const int*   verts = (const int*)d_in[0];
  const int*   ei    = (const int*)d_in[1];
  const float* ew    = (const float*)d_in[2];
  const float* emb   = (const float*)d_in[3];
  const float* wh    = (const float*)d_in[4];
  const float* w_out = (const float*)d_in[6];
  const float* bng_h = (const float*)d_in[8];
  const float* bnb_h = (const float*)d_in[9];
  const float* bng_o = (const float*)d_in[10];
  const float* bnb_o = (const float*)d_in[11];
  const float* tewl  = (const float*)d_in[12];
  const float* tewc  = (const float*)d_in[13];
  const float* teb   = (const float*)d_in[14];
  const float* maskw = (const float*)d_in[15];
  const float* maskb = (const float*)d_in[16];
  float* out = (float*)d_out;

  char* ws = (char*)d_ws;
  size_t off=0;
  auto alloc=[&](size_t bytes)->char*{ char* p = ws+off; off += (bytes+255)&~(size_t)255; return p; };
  unsigned int* sedge = (unsigned int*)alloc(sizeof(int)*LE);   // 22.4 MB
  int*   offs   = (int*)  alloc(sizeof(int)*(LN+1));            // 1.4 MB
  int*   Gm     = (int*)  alloc(sizeof(int)*LL*NBLK*GMS);       // 1.1 MB
  int*   S      = (int*)  alloc(sizeof(int)*(SCN+1));           // 1.1 MB
  int*   bsums  = (int*)  alloc(sizeof(int)*1024);
  unsigned short* xbf   = (unsigned short*)alloc(sizeof(short)*NN*DIM); // 12.8 MB
  unsigned short* supbf = (unsigned short*)alloc(sizeof(short)*NN*DIM); // 12.8 MB
  unsigned short* hbf   = (unsigned short*)alloc(sizeof(short)*NN*DIM); // 12.8 MB
  float* buf20  = (float*)alloc(sizeof(float)*NN*OUTC);         // 4 MB
  unsigned short* Wt = (unsigned short*)alloc(sizeof(short)*18*DIM*DIM);
  const int STATSZ = 6*NREP*256 + 8*64 + 8*32 + 256;
  float* stats  = (float*)alloc(sizeof(float)*STATSZ);
  float* ostat8 = stats + 6*NREP*256;  // [8][64]
  float* racc8  = ostat8 + 8*64;       // [8][32]
  float* bnso   = racc8 + 8*32;        // [scale128 | offset128]
  unsigned int*  btmpP = (unsigned int*)xbf;
  unsigned char* btmpD = (unsigned char*)hbf;

  // --- preprocessing: LDS-atomic counting sort (histogram shared bh->bscatter) ---
  hipMemsetAsync(stats, 0, sizeof(float)*STATSZ, stream);
  k_prep_w<<<1152,256,0,stream>>>(wh, tewl, tewc, Wt);
  k_bh<<<LL*NBLK,256,0,stream>>>(ei, Gm);
  int nsb = (SCN+4095)/4096;  // 68
  k_scan1p<<<nsb,256,0,stream>>>(Gm, S, bsums);
  k_scan2<<<1,1024,0,stream>>>(bsums, nsb);
  k_scan3<<<(SCN+255)/256,256,0,stream>>>(S, bsums);
  k_bscatter<<<LL*NBLK,256,0,stream>>>(ei, ew, S, Gm, btmpP, btmpD);
  k_fsort<<<LL*NBUK,256,0,stream>>>(btmpP, btmpD, S, sedge, offs);

  // --- 6 hidden layers; sup for layer i+1 computed inside gate2 of layer i ---
  k_gemm_sup_emb<<<(NN+31)/32,256,0,stream>>>(verts, emb, Wt, supbf, xbf, NN);
  for (int i=0;i<6;i++){
    int j = (i==0)?5:(i-1);
    float* stL = stats + i*NREP*256;
    k_spmm128<<<NN/8,256,0,stream>>>(supbf, sedge, offs, hbf, i*NN, stL);
    k_bnfin<<<1,256,0,stream>>>(stL, bng_h+(size_t)i*DIM, bnb_h+(size_t)i*DIM, bnso);
    if (i<5)
      k_gemm_gate2<1><<<(NN+63)/64,256,0,stream>>>(hbf, bnso,
          Wt + (size_t)(6+j)*DIM*DIM, Wt + (size_t)(12+j)*DIM*DIM,
          Wt + (size_t)(i+1)*DIM*DIM, teb + (size_t)j*DIM, xbf, supbf, NN);
    else
      k_gemm_gate2<0><<<(NN+63)/64,256,0,stream>>>(hbf, bnso,
          Wt + (size_t)(6+j)*DIM*DIM, Wt + (size_t)(12+j)*DIM*DIM,
          Wt, teb + (size_t)j*DIM, xbf, supbf, NN);
  }

  // --- output layer (fp32 accumulate) ---
  k_gemm_out<<<(NN+7)/8,256,0,stream>>>(xbf, w_out, buf20, NN);
  k_spmm_out<<<NN/8,256,0,stream>>>(buf20, sedge, offs, (float*)hbf, 6*NN);
  float* bufO = (float*)hbf;
  k_bn_stats_out<<<512,256,0,stream>>>(bufO, ostat8, 98);
  k_reduce<<<512,256,0,stream>>>(bufO, ostat8, bng_o, bnb_o, verts, maskw, racc8, 98);
  k_final<<<1,64,0,stream>>>(racc8, maskb, out);
}

// Round 5
// 742.026 us; speedup vs baseline: 3.6776x; 1.0009x over previous
//
#include <hip/hip_runtime.h>
#include <hip/hip_fp16.h>

#define NN 50000
#define EE 800000
#define DIM 128
#define OUTC 20
#define LL 7
#define LE (LL*EE)
#define LN (LL*NN)
#define BN_EPS 1e-5f
#define LSTRIDE 136     // bf16 elems per LDS row
#define NREP 64         // BN stat replicas
#define NBUK 196        // coarse buckets of 256 dsts per layer
#define GMS  200        // padded Gm stride
#define NBLK 200        // edge-blocks per layer (EE/NBLK = 4000)
#define CH   4000
#define CH4  (CH/4)
#define SCN  (LL*NBUK*NBLK)   // 274400 scan entries
#define FSCAP 4864      // fsort LDS staging capacity

typedef __attribute__((ext_vector_type(8))) short short8;
typedef __attribute__((ext_vector_type(4))) float f32x4;

static __device__ __forceinline__ float sigm(float z){ return 1.0f/(1.0f+expf(-z)); }
static __device__ __forceinline__ unsigned short f2bf(float f){
  unsigned int u = __float_as_uint(f);
  u += 0x7FFF + ((u>>16)&1);            // RNE
  return (unsigned short)(u>>16);
}
static __device__ __forceinline__ float bf2f(unsigned short s){
  return __uint_as_float(((unsigned int)s)<<16);
}

// ======== preprocessing: counting sort, all atomics in LDS, pure streaming ========

__global__ __launch_bounds__(256) void k_bh(const int* __restrict__ ei,
    int* __restrict__ Gm){
  int l = blockIdx.x / NBLK, b = blockIdx.x - l*NBLK;
  int t = threadIdx.x;
  __shared__ int h[NBUK];
  if (t<NBUK) h[t]=0;
  const int4* dsts = (const int4*)(ei + (size_t)(2*l+1)*EE + b*CH);
  int4 dv[4];
  #pragma unroll
  for (int i=0;i<4;i++){
    int k4 = t + i*256;
    if (k4<CH4) dv[i] = dsts[k4];
  }
  __syncthreads();
  #pragma unroll
  for (int i=0;i<4;i++){
    int k4 = t + i*256;
    if (k4<CH4){
      atomicAdd(&h[dv[i].x>>8], 1);
      atomicAdd(&h[dv[i].y>>8], 1);
      atomicAdd(&h[dv[i].z>>8], 1);
      atomicAdd(&h[dv[i].w>>8], 1);
    }
  }
  __syncthreads();
  int* g = Gm + (size_t)(l*NBLK+b)*GMS;
  if (t<NBUK) g[t]=h[t];
}

__global__ __launch_bounds__(256) void k_scan1p(const int* __restrict__ Gm,
    int* __restrict__ part, int* __restrict__ bsums){
  __shared__ int s[256];
  int t = threadIdx.x;
  int base = blockIdx.x*4096 + t*16;
  int v[16]; int sum = 0;
  #pragma unroll
  for (int i=0;i<16;i++){
    int idx = base+i; int val = 0;
    if (idx < SCN){
      int l = idx/(NBUK*NBLK);
      int r = idx - l*(NBUK*NBLK);
      int buk = r/NBLK, b = r - buk*NBLK;
      val = Gm[(size_t)(l*NBLK+b)*GMS + buk];
    }
    v[i]=val; sum+=val;
  }
  s[t]=sum; __syncthreads();
  for (int off=1; off<256; off<<=1){
    int x = (t>=off)? s[t-off] : 0;
    __syncthreads(); s[t]+=x; __syncthreads();
  }
  if (t==255) bsums[blockIdx.x] = s[255];
  int run = s[t]-sum;
  #pragma unroll
  for (int i=0;i<16;i++){ if (base+i<SCN) part[base+i]=run; run += v[i]; }
}

__global__ __launch_bounds__(1024) void k_scan2(int* bsums, int nb){
  __shared__ int s[1024];
  int t=threadIdx.x;
  int v = (t<nb)? bsums[t]:0;
  s[t]=v; __syncthreads();
  for (int off=1; off<1024; off<<=1){
    int x=(t>=off)? s[t-off]:0; __syncthreads(); s[t]+=x; __syncthreads();
  }
  if (t<nb) bsums[t] = s[t]-v;
}

__global__ void k_scan3(int* __restrict__ S, const int* __restrict__ bsums){
  int gid = blockIdx.x*256+threadIdx.x;
  if (gid < SCN) S[gid] += bsums[gid>>12];
  if (gid==0) S[SCN]=LE;
}

// P3: LDS counting-sort by bucket with FINAL payload stored at placement.
__global__ __launch_bounds__(256) void k_bscatter(const int* __restrict__ ei,
    const float* __restrict__ ew, const int* __restrict__ S,
    const int* __restrict__ Gm,
    unsigned int* __restrict__ btmpP, unsigned char* __restrict__ btmpD){
  int l = blockIdx.x / NBLK, b = blockIdx.x - l*NBLK;
  int t = threadIdx.x;
  __shared__ int bstart[NBUK], cur[NBUK], runb[NBUK];
  __shared__ int ps[256];
  __shared__ unsigned int  ebP[CH];     // 16 KB: src16|halfw16
  __shared__ unsigned short ebM[CH];    // 8 KB:  dlow8|buk8
  const int4*   srcs = (const int4*)(ei + (size_t)(2*l)*EE + b*CH);
  const int4*   dsts = (const int4*)(ei + (size_t)(2*l+1)*EE + b*CH);
  const float4* wsrc = (const float4*)(ew + (size_t)l*EE + b*CH);
  int4 sv[4], dv[4]; float4 wv[4];
  #pragma unroll
  for (int i=0;i<4;i++){
    int k4 = t + i*256;
    if (k4<CH4){
      sv[i] = srcs[k4];
      dv[i] = dsts[k4];
      wv[i] = wsrc[k4];
    }
  }
  int v = (t<NBUK)? Gm[(size_t)(l*NBLK+b)*GMS + t] : 0;
  ps[t]=v; __syncthreads();
  for (int o=1;o<256;o<<=1){ int x=(t>=o)?ps[t-o]:0; __syncthreads(); ps[t]+=x; __syncthreads(); }
  if (t<NBUK){ bstart[t]=ps[t]-v; cur[t]=ps[t]-v; runb[t] = S[(size_t)(l*NBUK+t)*NBLK + b]; }
  __syncthreads();
  #define PUTE(SRC,DST,WF) { int buk=(DST)>>8; int pos=atomicAdd(&cur[buk],1); \
    unsigned short hw=__half_as_ushort(__float2half(WF)); \
    ebP[pos]=(unsigned)(SRC)|((unsigned)hw<<16); \
    ebM[pos]=(unsigned short)(((DST)&255)|(buk<<8)); }
  #pragma unroll
  for (int i=0;i<4;i++){
    int k4 = t + i*256;
    if (k4<CH4){
      PUTE(sv[i].x, dv[i].x, wv[i].x);
      PUTE(sv[i].y, dv[i].y, wv[i].y);
      PUTE(sv[i].z, dv[i].z, wv[i].z);
      PUTE(sv[i].w, dv[i].w, wv[i].w);
    }
  }
  #undef PUTE
  __syncthreads();
  for (int k=t;k<CH;k+=256){
    unsigned short m = ebM[k];
    int buk = m>>8;
    int gp = runb[buk] + (k - bstart[buk]);
    btmpP[gp] = ebP[k];
    btmpD[gp] = (unsigned char)(m&255);
  }
}

// P4: per-bucket count+scan; scatter staged through LDS for coalesced writeback.
__global__ __launch_bounds__(256) void k_fsort(const unsigned int* __restrict__ btmpP,
    const unsigned char* __restrict__ btmpD, const int* __restrict__ S,
    unsigned int* __restrict__ sedge, int* __restrict__ offs){
  int lbuk = blockIdx.x;
  int l = lbuk/NBUK, bl = lbuk - l*NBUK;
  int t = threadIdx.x;
  int base = S[(size_t)lbuk*NBLK];
  int end  = S[(size_t)(lbuk+1)*NBLK];
  int nE = end - base;
  __shared__ int cnt[256], sc[256];
  __shared__ unsigned int stg[FSCAP];
  cnt[t]=0;
  __syncthreads();
  for (int k=t; k<nE; k+=256) atomicAdd(&cnt[btmpD[base+k]], 1);
  __syncthreads();
  int c = cnt[t];
  sc[t]=c;
  __syncthreads();
  for (int o=1;o<256;o<<=1){
    int v = (t>=o)? sc[t-o]:0;
    __syncthreads();
    sc[t]+=v;
    __syncthreads();
  }
  int excl = sc[t]-c;
  {
    int node = bl*256+t;
    if (node<NN) offs[(size_t)l*NN+node] = base + excl;
  }
  if (lbuk==0 && t==255) offs[LN]=LE;
  if (nE <= FSCAP){
    cnt[t] = excl;                 // LDS-relative running cursor
    __syncthreads();
    for (int k=t; k<nE; k+=256){
      int d = btmpD[base+k];
      int r = atomicAdd(&cnt[d],1);
      stg[r] = btmpP[base+k];
    }
    __syncthreads();
    for (int k=t; k<nE; k+=256) sedge[base+k] = stg[k];   // coalesced writeback
  } else {
    cnt[t] = base + excl;          // fallback: direct global scatter
    __syncthreads();
    for (int k=t; k<nE; k+=256){
      int d = btmpD[base+k];
      int r = atomicAdd(&cnt[d],1);
      sedge[r] = btmpP[base+k];
    }
  }
}

// ---- transpose + bf16-convert all 18 hidden weight matrices: Wt[m][n][k] ----
__global__ __launch_bounds__(256) void k_prep_w(const float* __restrict__ wh,
    const float* __restrict__ tewl, const float* __restrict__ tewc,
    unsigned short* __restrict__ Wt){
  int gid = blockIdx.x*256+threadIdx.x;
  int m = gid>>14; int idx = gid&16383;
  int n = idx>>7, k = idx&127;
  const float* src = (m<6)? wh + (size_t)m*16384
                   : (m<12)? tewl + (size_t)(m-6)*16384
                   : tewc + (size_t)(m-12)*16384;
  Wt[gid] = f2bf(src[k*128+n]);
}

// -------- MFMA GEMM layer 0 (32-row tiles): gather emb, write xbf, compute sup --------
__global__ __launch_bounds__(256) void k_gemm_sup_emb(const int* __restrict__ verts,
    const float* __restrict__ emb, const unsigned short* __restrict__ Wt,
    unsigned short* __restrict__ Y, unsigned short* __restrict__ xout, int M){
  __shared__ unsigned short Xs[32*LSTRIDE];
  int tid = threadIdx.x;
  int row0 = blockIdx.x*32;
  #pragma unroll
  for (int it=0; it<2; it++){
    int idx = tid + it*256;
    int r = idx>>4, k8 = idx&15;
    short8 w = short8(0);
    if (row0+r < M){
      int v = verts[row0+r];
      const float4* p = (const float4*)emb + (size_t)v*32 + k8*2;
      float4 v0 = p[0], v1 = p[1];
      w[0]=(short)f2bf(v0.x); w[1]=(short)f2bf(v0.y); w[2]=(short)f2bf(v0.z); w[3]=(short)f2bf(v0.w);
      w[4]=(short)f2bf(v1.x); w[5]=(short)f2bf(v1.y); w[6]=(short)f2bf(v1.z); w[7]=(short)f2bf(v1.w);
      *(short8*)(xout + (size_t)(row0+r)*128 + k8*8) = w;
    }
    *(short8*)&Xs[r*LSTRIDE + k8*8] = w;
  }
  __syncthreads();
  int w = tid>>6, lane = tid&63, m = lane&15, q = lane>>4;
  int rw = (w&1)*16, cw = (w>>1)*64;
  f32x4 acc[4];
  #pragma unroll
  for (int nt=0;nt<4;nt++){ acc[nt][0]=0.f; acc[nt][1]=0.f; acc[nt][2]=0.f; acc[nt][3]=0.f; }
  #pragma unroll
  for (int kc=0; kc<4; kc++){
    short8 a = *(const short8*)&Xs[(rw+m)*LSTRIDE + kc*32 + 8*q];
    #pragma unroll
    for (int nt=0; nt<4; nt++){
      short8 b = *(const short8*)&Wt[(size_t)(cw+nt*16+m)*128 + kc*32 + 8*q];
      acc[nt] = __builtin_amdgcn_mfma_f32_16x16x32_bf16(a, b, acc[nt], 0,0,0);
    }
  }
  #pragma unroll
  for (int nt=0; nt<4; nt++){
    #pragma unroll
    for (int i=0;i<4;i++){
      int rr = row0 + rw + 4*q + i;
      if (rr<M) Y[(size_t)rr*128 + cw + nt*16 + m] = f2bf(acc[nt][i]);
    }
  }
}

// ------- fused gate, 64-row tiles; BN replica-reduce in-block (R1-proven-free) -------
template<int FUSE>
__global__ __launch_bounds__(256,4) void k_gemm_gate2(const unsigned short* __restrict__ H,
    const float* __restrict__ stL,            // NREP replicas [rep][sum128|sq128]
    const float* __restrict__ gamma, const float* __restrict__ beta,
    const unsigned short* __restrict__ Wl, const unsigned short* __restrict__ Wc,
    const unsigned short* __restrict__ Wn, const float* __restrict__ teb,
    unsigned short* __restrict__ x, unsigned short* __restrict__ supY, int M){
  __shared__ unsigned short XsX[64*LSTRIDE];
  __shared__ unsigned short XsH[64*LSTRIDE];
  __shared__ float sSc[128], sOff[128];
  int tid = threadIdx.x;
  int row0 = blockIdx.x*64;
  int k8 = tid&15;   // feature chunk, same for all 4 row-quarters
  // front-load ALL global reads before any barrier
  short8 xv[4], hv[4];
  #pragma unroll
  for (int it=0; it<4; it++){
    int r = (tid + it*256)>>4;
    xv[it] = short8(0); hv[it] = short8(0);
    if (row0+r < M){
      xv[it] = *(const short8*)(x + (size_t)(row0+r)*128 + k8*8);
      hv[it] = *(const short8*)(H + (size_t)(row0+r)*128 + k8*8);
    }
  }
  if (tid<128){
    float s=0.f, sq=0.f;
    #pragma unroll 8
    for (int g=0; g<NREP; g++){ s += stL[g*256+tid]; sq += stL[g*256+128+tid]; }
    float mean = s*(1.0f/NN);
    float var = sq*(1.0f/NN) - mean*mean;
    float sc = rsqrtf(var+BN_EPS)*gamma[tid];
    sSc[tid]=sc; sOff[tid]=beta[tid]-mean*sc;
  }
  #pragma unroll
  for (int it=0; it<4; it++){
    int r = (tid + it*256)>>4;
    *(short8*)&XsX[r*LSTRIDE + k8*8] = xv[it];
  }
  __syncthreads();
  #pragma unroll
  for (int it=0; it<4; it++){
    int r = (tid + it*256)>>4;
    int k = k8*8;
    short8 w;
    #pragma unroll
    for (int j=0;j<8;j++){
      float o = bf2f((unsigned short)hv[it][j]);
      w[j] = (short)f2bf(fmaxf(fmaf(o, sSc[k+j], sOff[k+j]), 0.f));
    }
    *(short8*)&XsH[r*LSTRIDE + k8*8] = w;
  }
  __syncthreads();
  int w = tid>>6, lane = tid&63, m = lane&15, q = lane>>4;
  int rw = (w>>1)*16, cw = (w&1)*64;   // rows {rw..rw+15, rw+32..rw+47}, cols cw..cw+63
  f32x4 acc[2][4];
  #pragma unroll
  for (int rt=0;rt<2;rt++)
    #pragma unroll
    for (int nt=0;nt<4;nt++){ acc[rt][nt][0]=0.f; acc[rt][nt][1]=0.f; acc[rt][nt][2]=0.f; acc[rt][nt][3]=0.f; }
  #pragma unroll
  for (int kc=0; kc<4; kc++){
    short8 a0 = *(const short8*)&XsX[(rw+m)*LSTRIDE + kc*32 + 8*q];
    short8 a1 = *(const short8*)&XsX[(rw+32+m)*LSTRIDE + kc*32 + 8*q];
    #pragma unroll
    for (int nt=0; nt<4; nt++){
      short8 b = *(const short8*)&Wl[(size_t)(cw+nt*16+m)*128 + kc*32 + 8*q];
      acc[0][nt] = __builtin_amdgcn_mfma_f32_16x16x32_bf16(a0, b, acc[0][nt], 0,0,0);
      acc[1][nt] = __builtin_amdgcn_mfma_f32_16x16x32_bf16(a1, b, acc[1][nt], 0,0,0);
    }
  }
  #pragma unroll
  for (int kc=0; kc<4; kc++){
    short8 a0 = *(const short8*)&XsH[(rw+m)*LSTRIDE + kc*32 + 8*q];
    short8 a1 = *(const short8*)&XsH[(rw+32+m)*LSTRIDE + kc*32 + 8*q];
    #pragma unroll
    for (int nt=0; nt<4; nt++){
      short8 b = *(const short8*)&Wc[(size_t)(cw+nt*16+m)*128 + kc*32 + 8*q];
      acc[0][nt] = __builtin_amdgcn_mfma_f32_16x16x32_bf16(a0, b, acc[0][nt], 0,0,0);
      acc[1][nt] = __builtin_amdgcn_mfma_f32_16x16x32_bf16(a1, b, acc[1][nt], 0,0,0);
    }
  }
  __syncthreads();   // all MFMA A-reads done before epilogue overwrites LDS (race fix)
  // gate epilogue: each (lr,col) cell owned by exactly one thread
  #pragma unroll
  for (int rt=0; rt<2; rt++){
    #pragma unroll
    for (int nt=0; nt<4; nt++){
      int col = cw + nt*16 + m;
      float bias = teb[col];
      #pragma unroll
      for (int i=0;i<4;i++){
        int lr = rw + rt*32 + 4*q + i;
        float hvv = bf2f(XsH[lr*LSTRIDE + col]);
        float xo  = bf2f(XsX[lr*LSTRIDE + col]);
        float g = sigm(acc[rt][nt][i] + bias);
        unsigned short xnb = f2bf(g*hvv + (1.f-g)*xo);
        XsH[lr*LSTRIDE + col] = xnb;
        if (FUSE) XsX[lr*LSTRIDE + col] = xnb;
      }
    }
  }
  __syncthreads();
  // coalesced short8 writeback of x_new
  #pragma unroll
  for (int it=0; it<4; it++){
    int r = (tid + it*256)>>4;
    if (row0+r < M)
      *(short8*)(x + (size_t)(row0+r)*128 + k8*8) = *(short8*)&XsH[r*LSTRIDE + k8*8];
  }
  if (FUSE){
    #pragma unroll
    for (int rt=0;rt<2;rt++)
      #pragma unroll
      for (int nt=0;nt<4;nt++){ acc[rt][nt][0]=0.f; acc[rt][nt][1]=0.f; acc[rt][nt][2]=0.f; acc[rt][nt][3]=0.f; }
    #pragma unroll
    for (int kc=0; kc<4; kc++){
      short8 a0 = *(const short8*)&XsX[(rw+m)*LSTRIDE + kc*32 + 8*q];
      short8 a1 = *(const short8*)&XsX[(rw+32+m)*LSTRIDE + kc*32 + 8*q];
      #pragma unroll
      for (int nt=0; nt<4; nt++){
        short8 b = *(const short8*)&Wn[(size_t)(cw+nt*16+m)*128 + kc*32 + 8*q];
        acc[0][nt] = __builtin_amdgcn_mfma_f32_16x16x32_bf16(a0, b, acc[0][nt], 0,0,0);
        acc[1][nt] = __builtin_amdgcn_mfma_f32_16x16x32_bf16(a1, b, acc[1][nt], 0,0,0);
      }
    }
    #pragma unroll
    for (int rt=0; rt<2; rt++){
      #pragma unroll
      for (int nt=0; nt<4; nt++){
        #pragma unroll
        for (int i=0;i<4;i++){
          int rr = row0 + rw + rt*32 + 4*q + i;
          if (rr<M) supY[(size_t)rr*128 + cw + nt*16 + m] = f2bf(acc[rt][nt][i]);
        }
      }
    }
  }
}

// ---------------- Y[M,20] = bf16 X[M,128] @ W[128,20] (fp32 acc) ----------------
__global__ __launch_bounds__(256) void k_gemm_out(const unsigned short* __restrict__ X,
    const float* __restrict__ W, float* __restrict__ Y, int M){
  __shared__ float Ws[DIM*OUTC];
  __shared__ float Xs2[8*DIM];
  int tid=threadIdx.x;
  for (int i=tid;i<DIM*OUTC;i+=256) Ws[i]=W[i];
  int row0=blockIdx.x*8;
  if (tid<128){
    int r = tid>>4, k8 = tid&15;
    short8 v = short8(0);
    if (row0+r<M) v = *(const short8*)(X + (size_t)(row0+r)*128 + k8*8);
    #pragma unroll
    for (int j=0;j<8;j++) Xs2[r*DIM+k8*8+j] = bf2f((unsigned short)v[j]);
  }
  __syncthreads();
  int c = tid&31, rl=tid>>5;
  if (c<OUTC && row0+rl<M){
    float acc=0.f;
    #pragma unroll 8
    for (int k=0;k<DIM;k++) acc += Xs2[rl*DIM+k]*Ws[k*OUTC+c];
    Y[(size_t)(row0+rl)*OUTC+c]=acc;
  }
}

// -------- SpMM gather (contiguous per-node edges, 8-deep unroll) + fused BN stats --------
// (exact round-2 body: do NOT add tail code here — it wrecks regalloc of the gather loop)
__global__ __launch_bounds__(256) void k_spmm128(const unsigned short* __restrict__ sup,
    const unsigned int* __restrict__ sedge, const int* __restrict__ offs,
    unsigned short* __restrict__ h, int lbase, float* __restrict__ stL){
  int nl = threadIdx.x>>5;
  int node = blockIdx.x*8 + nl;
  int fq = threadIdx.x & 31;
  int p = offs[lbase+node], end = offs[lbase+node+1];
  float4 a0 = make_float4(0.f,0.f,0.f,0.f), a1 = a0, a2 = a0, a3 = a0;
  for (; p+7<end; p+=8){
    unsigned int ev[8];
    #pragma unroll
    for (int u=0;u<8;u++) ev[u] = __builtin_nontemporal_load(sedge+p+u);
    ushort4 sv[8];
    #pragma unroll
    for (int u=0;u<8;u++) sv[u] = *(const ushort4*)(sup + (size_t)(ev[u]&0xFFFFu)*128 + fq*4);
    #pragma unroll
    for (int u=0;u<8;u++){
      float w = __half2float(__ushort_as_half((unsigned short)(ev[u]>>16)));
      float4& a = (u&3)==0? a0 : (u&3)==1? a1 : (u&3)==2? a2 : a3;
      a.x += w*bf2f(sv[u].x); a.y += w*bf2f(sv[u].y);
      a.z += w*bf2f(sv[u].z); a.w += w*bf2f(sv[u].w);
    }
  }
  for (; p+3<end; p+=4){
    unsigned int e0 = __builtin_nontemporal_load(sedge+p);
    unsigned int e1 = __builtin_nontemporal_load(sedge+p+1);
    unsigned int e2 = __builtin_nontemporal_load(sedge+p+2);
    unsigned int e3 = __builtin_nontemporal_load(sedge+p+3);
    ushort4 s0 = *(const ushort4*)(sup + (size_t)(e0&0xFFFFu)*128 + fq*4);
    ushort4 s1 = *(const ushort4*)(sup + (size_t)(e1&0xFFFFu)*128 + fq*4);
    ushort4 s2 = *(const ushort4*)(sup + (size_t)(e2&0xFFFFu)*128 + fq*4);
    ushort4 s3 = *(const ushort4*)(sup + (size_t)(e3&0xFFFFu)*128 + fq*4);
    float w0 = __half2float(__ushort_as_half((unsigned short)(e0>>16)));
    float w1 = __half2float(__ushort_as_half((unsigned short)(e1>>16)));
    float w2 = __half2float(__ushort_as_half((unsigned short)(e2>>16)));
    float w3 = __half2float(__ushort_as_half((unsigned short)(e3>>16)));
    a0.x += w0*bf2f(s0.x); a0.y += w0*bf2f(s0.y); a0.z += w0*bf2f(s0.z); a0.w += w0*bf2f(s0.w);
    a1.x += w1*bf2f(s1.x); a1.y += w1*bf2f(s1.y); a1.z += w1*bf2f(s1.z); a1.w += w1*bf2f(s1.w);
    a2.x += w2*bf2f(s2.x); a2.y += w2*bf2f(s2.y); a2.z += w2*bf2f(s2.z); a2.w += w2*bf2f(s2.w);
    a3.x += w3*bf2f(s3.x); a3.y += w3*bf2f(s3.y); a3.z += w3*bf2f(s3.z); a3.w += w3*bf2f(s3.w);
  }
  for (; p<end; p++){
    unsigned int e0 = __builtin_nontemporal_load(sedge+p);
    float w0 = __half2float(__ushort_as_half((unsigned short)(e0>>16)));
    ushort4 s0 = *(const ushort4*)(sup + (size_t)(e0&0xFFFFu)*128 + fq*4);
    a0.x += w0*bf2f(s0.x); a0.y += w0*bf2f(s0.y); a0.z += w0*bf2f(s0.z); a0.w += w0*bf2f(s0.w);
  }
  a0.x+=a1.x+a2.x+a3.x; a0.y+=a1.y+a2.y+a3.y;
  a0.z+=a1.z+a2.z+a3.z; a0.w+=a1.w+a2.w+a3.w;
  ushort4 ov;
  ov.x=f2bf(a0.x); ov.y=f2bf(a0.y); ov.z=f2bf(a0.z); ov.w=f2bf(a0.w);
  *(ushort4*)(h + (size_t)node*128 + fq*4) = ov;
  __shared__ float sP[8][132], sQ[8][132];
  int f0 = fq*4;
  sP[nl][f0+0]=a0.x; sP[nl][f0+1]=a0.y; sP[nl][f0+2]=a0.z; sP[nl][f0+3]=a0.w;
  sQ[nl][f0+0]=a0.x*a0.x; sQ[nl][f0+1]=a0.y*a0.y; sQ[nl][f0+2]=a0.z*a0.z; sQ[nl][f0+3]=a0.w*a0.w;
  __syncthreads();
  if (threadIdx.x < 128){
    int f = threadIdx.x;
    float s=0.f, sq=0.f;
    #pragma unroll
    for (int n=0;n<8;n++){ s += sP[n][f]; sq += sQ[n][f]; }
    float* base = stL + (blockIdx.x & (NREP-1))*256;
    atomicAdd(&base[f], s); atomicAdd(&base[128+f], sq);
  }
}

// -------- output SpMM (8-deep unroll) + fused output-BN stats tail --------
__global__ __launch_bounds__(256) void k_spmm_out(const float* __restrict__ sup,
    const unsigned int* __restrict__ sedge, const int* __restrict__ offs,
    float* __restrict__ h, int lbase, float* __restrict__ st8){
  int nl = threadIdx.x>>5;
  int node = blockIdx.x*8 + nl;
  int c = threadIdx.x & 31;
  bool act = c < OUTC;
  int p = offs[lbase+node], end = offs[lbase+node+1];
  float a0=0.f,a1=0.f,a2=0.f,a3=0.f;
  for (; p+7<end; p+=8){
    unsigned int ev[8];
    #pragma unroll
    for (int u=0;u<8;u++) ev[u] = __builtin_nontemporal_load(sedge+p+u);
    float sv[8];
    #pragma unroll
    for (int u=0;u<8;u++) sv[u] = act ? sup[(size_t)(ev[u]&0xFFFFu)*OUTC+c] : 0.f;
    #pragma unroll
    for (int u=0;u<8;u++){
      float w = __half2float(__ushort_as_half((unsigned short)(ev[u]>>16)));
      if ((u&3)==0) a0 += w*sv[u];
      else if ((u&3)==1) a1 += w*sv[u];
      else if ((u&3)==2) a2 += w*sv[u];
      else a3 += w*sv[u];
    }
  }
  for (; p<end; p++){
    unsigned int e = __builtin_nontemporal_load(sedge+p);
    float w = __half2float(__ushort_as_half((unsigned short)(e>>16)));
    float sv = act ? sup[(size_t)(e&0xFFFFu)*OUTC+c] : 0.f;
    a0 += w*sv;
  }
  float v = a0+a1+a2+a3;
  if (act) h[(size_t)node*OUTC+c] = v;
  if (!act) v = 0.f;
  __shared__ float sS[8][33], sQ[8][33];
  sS[nl][c] = v; sQ[nl][c] = v*v;
  __syncthreads();
  if (threadIdx.x < 32){
    float s=0.f, sq=0.f;
    #pragma unroll
    for (int n=0;n<8;n++){ s += sS[n][c]; sq += sQ[n][c]; }
    if (c<OUTC){
      float* base = st8 + (blockIdx.x&7)*64;
      atomicAdd(&base[c], s); atomicAdd(&base[32+c], sq);
    }
  }
}

// ---------- fused: BN-normalize+ReLU inline + masked reduce (8-way replicated) ----------
__global__ __launch_bounds__(256) void k_reduce(const float* __restrict__ xf,
    const float* __restrict__ st8, const float* __restrict__ gamma,
    const float* __restrict__ beta, const int* __restrict__ verts,
    const float* __restrict__ mw, float* __restrict__ acc8, int rpb){
  int c = threadIdx.x & 31, g = threadIdx.x >> 5;
  float scn=0.f, offc=0.f;
  if (c<OUTC){
    float s=0.f, sq=0.f;
    #pragma unroll
    for (int i=0;i<8;i++){ s += st8[i*64+c]; sq += st8[i*64+32+c]; }
    const float invN = 1.0f/NN;
    float m = s*invN;
    float var = sq*invN - m*m;
    scn = rsqrtf(var+BN_EPS)*gamma[c];
    offc = beta[c] - m*scn;
  }
  int r0 = blockIdx.x*rpb;
  int r1 = min(NN, r0+rpb);
  float s=0.f;
  for (int r=r0+g; r<r1; r+=8){
    float m = mw[verts[r]];
    if (c<OUTC){
      float v = fmaxf(fmaf(xf[(size_t)r*OUTC+c], scn, offc), 0.f);
      s += m * v;
    }
  }
  __shared__ float sh[256];
  sh[threadIdx.x]=s; __syncthreads();
  if (threadIdx.x<32){
    #pragma unroll
    for (int i=1;i<8;i++) s += sh[threadIdx.x + i*32];
    if (c<OUTC) atomicAdd(&acc8[(blockIdx.x&7)*32 + c], s);
  }
}

__global__ void k_final(const float* __restrict__ acc8, const float* __restrict__ mb,
                        float* __restrict__ out){
  int c=threadIdx.x;
  if (c<OUTC){
    float s=0.f;
    #pragma unroll
    for (int g=0; g<8; g++) s += acc8[g*32+c];
    out[c] = sigm(s+mb[c]);
  }
}

// ---------------- host ----------------
extern "C" void kernel_launch(void* const* d_in, const int* in_sizes, int n_in,
                              void* d_out, int out_size, void* d_ws, size_t ws_size,
                              hipStream_t stream){
  const int*   verts = (const int*)d_in[0];
  const int*   ei    = (const int*)d_in[1];
  const float* ew    = (const float*)d_in[2];
  const float* emb   = (const float*)d_in[3];
  const float* wh    = (const float*)d_in[4];
  const float* w_out = (const float*)d_in[6];
  const float* bng_h = (const float*)d_in[8];
  const float* bnb_h = (const float*)d_in[9];
  const float* bng_o = (const float*)d_in[10];
  const float* bnb_o = (const float*)d_in[11];
  const float* tewl  = (const float*)d_in[12];
  const float* tewc  = (const float*)d_in[13];
  const float* teb   = (const float*)d_in[14];
  const float* maskw = (const float*)d_in[15];
  const float* maskb = (const float*)d_in[16];
  float* out = (float*)d_out;

  char* ws = (char*)d_ws;
  size_t off=0;
  auto alloc=[&](size_t bytes)->char*{ char* p = ws+off; off += (bytes+255)&~(size_t)255; return p; };
  unsigned int* sedge = (unsigned int*)alloc(sizeof(int)*LE);   // 22.4 MB
  int*   offs   = (int*)  alloc(sizeof(int)*(LN+1));            // 1.4 MB
  int*   Gm     = (int*)  alloc(sizeof(int)*LL*NBLK*GMS);       // 1.1 MB
  int*   S      = (int*)  alloc(sizeof(int)*(SCN+1));           // 1.1 MB
  int*   bsums  = (int*)  alloc(sizeof(int)*1024);
  unsigned short* xbf   = (unsigned short*)alloc(sizeof(short)*NN*DIM); // 12.8 MB
  unsigned short* supbf = (unsigned short*)alloc(sizeof(short)*NN*DIM); // 12.8 MB
  unsigned short* hbf   = (unsigned short*)alloc(sizeof(short)*NN*DIM); // 12.8 MB
  float* buf20  = (float*)alloc(sizeof(float)*NN*OUTC);         // 4 MB
  unsigned short* Wt = (unsigned short*)alloc(sizeof(short)*18*DIM*DIM);
  const int STATSZ = 6*NREP*256 + 8*64 + 8*32;
  float* stats  = (float*)alloc(sizeof(float)*STATSZ);
  float* ostat8 = stats + 6*NREP*256;  // [8][64]
  float* racc8  = ostat8 + 8*64;       // [8][32]
  unsigned int*  btmpP = (unsigned int*)xbf;
  unsigned char* btmpD = (unsigned char*)hbf;

  // --- preprocessing: LDS-atomic counting sort (histogram shared bh->bscatter) ---
  hipMemsetAsync(stats, 0, sizeof(float)*STATSZ, stream);
  k_prep_w<<<1152,256,0,stream>>>(wh, tewl, tewc, Wt);
  k_bh<<<LL*NBLK,256,0,stream>>>(ei, Gm);
  int nsb = (SCN+4095)/4096;  // 68
  k_scan1p<<<nsb,256,0,stream>>>(Gm, S, bsums);
  k_scan2<<<1,1024,0,stream>>>(bsums, nsb);
  k_scan3<<<(SCN+255)/256,256,0,stream>>>(S, bsums);
  k_bscatter<<<LL*NBLK,256,0,stream>>>(ei, ew, S, Gm, btmpP, btmpD);
  k_fsort<<<LL*NBUK,256,0,stream>>>(btmpP, btmpD, S, sedge, offs);

  // --- 6 hidden layers; sup for layer i+1 computed inside gate2 of layer i ---
  k_gemm_sup_emb<<<(NN+31)/32,256,0,stream>>>(verts, emb, Wt, supbf, xbf, NN);
  for (int i=0;i<6;i++){
    int j = (i==0)?5:(i-1);
    float* stL = stats + i*NREP*256;
    k_spmm128<<<NN/8,256,0,stream>>>(supbf, sedge, offs, hbf, i*NN, stL);
    if (i<5)
      k_gemm_gate2<1><<<(NN+63)/64,256,0,stream>>>(hbf, stL,
          bng_h+(size_t)i*DIM, bnb_h+(size_t)i*DIM,
          Wt + (size_t)(6+j)*DIM*DIM, Wt + (size_t)(12+j)*DIM*DIM,
          Wt + (size_t)(i+1)*DIM*DIM, teb + (size_t)j*DIM, xbf, supbf, NN);
    else
      k_gemm_gate2<0><<<(NN+63)/64,256,0,stream>>>(hbf, stL,
          bng_h+(size_t)i*DIM, bnb_h+(size_t)i*DIM,
          Wt + (size_t)(6+j)*DIM*DIM, Wt + (size_t)(12+j)*DIM*DIM,
          Wt, teb + (size_t)j*DIM, xbf, supbf, NN);
  }

  // --- output layer (fp32 accumulate) ---
  k_gemm_out<<<(NN+7)/8,256,0,stream>>>(xbf, w_out, buf20, NN);
  k_spmm_out<<<NN/8,256,0,stream>>>(buf20, sedge, offs, (float*)hbf, 6*NN, ostat8);
  float* bufO = (float*)hbf;
  k_reduce<<<512,256,0,stream>>>(bufO, ostat8, bng_o, bnb_o, verts, maskw, racc8, 98);
  k_final<<<1,64,0,stream>>>(racc8, maskb, out);
}

// Round 6
// 702.452 us; speedup vs baseline: 3.8848x; 1.0563x over previous
//
#include <hip/hip_runtime.h>
#include <hip/hip_fp16.h>

#define NN 50000
#define EE 800000
#define DIM 128
#define OUTC 20
#define LL 7
#define LE (LL*EE)
#define LN (LL*NN)
#define BN_EPS 1e-5f
#define LSTRIDE 136     // bf16 elems per LDS row
#define NREP 64         // BN stat replicas
#define NBUK 196        // coarse buckets of 256 dsts per layer
#define GMS  200        // padded Gm stride
#define NBLK 200        // edge-blocks per layer (EE/NBLK = 4000)
#define CH   4000
#define CH4  (CH/4)
#define SCN  (LL*NBUK*NBLK)   // 274400 scan entries
#define FSCAP 4864      // fsort LDS staging capacity
#define STATSZ (6*NREP*256 + 8*64 + 8*32)   // 99072 floats
#define STATSZ4 (STATSZ/4)

typedef __attribute__((ext_vector_type(8))) short short8;
typedef __attribute__((ext_vector_type(4))) float f32x4;

static __device__ __forceinline__ float sigm(float z){ return 1.0f/(1.0f+expf(-z)); }
static __device__ __forceinline__ unsigned short f2bf(float f){
  unsigned int u = __float_as_uint(f);
  u += 0x7FFF + ((u>>16)&1);            // RNE
  return (unsigned short)(u>>16);
}
static __device__ __forceinline__ float bf2f(unsigned short s){
  return __uint_as_float(((unsigned int)s)<<16);
}

// ======== fused prologue: weight transpose+cvt, dst histogram, stats zero ========
// blocks [0,1152): Wt transpose; [1152,1168): WtOut; [1168,2568): bh; [2568,2665): zero stats
__global__ __launch_bounds__(256) void k_pre(const float* __restrict__ wh,
    const float* __restrict__ tewl, const float* __restrict__ tewc,
    const float* __restrict__ wout,
    unsigned short* __restrict__ Wt, unsigned short* __restrict__ WtO,
    const int* __restrict__ ei, int* __restrict__ Gm, float* __restrict__ stats){
  int bid = blockIdx.x;
  int t = threadIdx.x;
  if (bid < 1152){
    int gid = bid*256+t;
    int m = gid>>14; int idx = gid&16383;
    int n = idx>>7, k = idx&127;
    const float* src = (m<6)? wh + (size_t)m*16384
                     : (m<12)? tewl + (size_t)(m-6)*16384
                     : tewc + (size_t)(m-12)*16384;
    Wt[gid] = f2bf(src[k*128+n]);
  } else if (bid < 1168){
    int idx = (bid-1152)*256+t;       // 0..4095 over [32][128]
    int n = idx>>7, k = idx&127;
    WtO[idx] = (n<OUTC)? f2bf(wout[k*OUTC+n]) : (unsigned short)0;
  } else if (bid < 2568){
    int bb = bid-1168;
    int l = bb / NBLK, b = bb - l*NBLK;
    __shared__ int h[NBUK];
    if (t<NBUK) h[t]=0;
    const int4* dsts = (const int4*)(ei + (size_t)(2*l+1)*EE + b*CH);
    int4 dv[4];
    #pragma unroll
    for (int i=0;i<4;i++){
      int k4 = t + i*256;
      if (k4<CH4) dv[i] = dsts[k4];
    }
    __syncthreads();
    #pragma unroll
    for (int i=0;i<4;i++){
      int k4 = t + i*256;
      if (k4<CH4){
        atomicAdd(&h[dv[i].x>>8], 1);
        atomicAdd(&h[dv[i].y>>8], 1);
        atomicAdd(&h[dv[i].z>>8], 1);
        atomicAdd(&h[dv[i].w>>8], 1);
      }
    }
    __syncthreads();
    int* g = Gm + (size_t)(l*NBLK+b)*GMS;
    if (t<NBUK) g[t]=h[t];
  } else {
    int z = (bid-2568)*256+t;
    if (z < STATSZ4) ((float4*)stats)[z] = make_float4(0.f,0.f,0.f,0.f);
  }
}

__global__ __launch_bounds__(256) void k_scan1p(const int* __restrict__ Gm,
    int* __restrict__ part, int* __restrict__ bsums){
  __shared__ int s[256];
  int t = threadIdx.x;
  int base = blockIdx.x*4096 + t*16;
  int v[16]; int sum = 0;
  #pragma unroll
  for (int i=0;i<16;i++){
    int idx = base+i; int val = 0;
    if (idx < SCN){
      int l = idx/(NBUK*NBLK);
      int r = idx - l*(NBUK*NBLK);
      int buk = r/NBLK, b = r - buk*NBLK;
      val = Gm[(size_t)(l*NBLK+b)*GMS + buk];
    }
    v[i]=val; sum+=val;
  }
  s[t]=sum; __syncthreads();
  for (int off=1; off<256; off<<=1){
    int x = (t>=off)? s[t-off] : 0;
    __syncthreads(); s[t]+=x; __syncthreads();
  }
  if (t==255) bsums[blockIdx.x] = s[255];
  int run = s[t]-sum;
  #pragma unroll
  for (int i=0;i<16;i++){ if (base+i<SCN) part[base+i]=run; run += v[i]; }
}

__global__ __launch_bounds__(1024) void k_scan2(int* bsums, int nb){
  __shared__ int s[1024];
  int t=threadIdx.x;
  int v = (t<nb)? bsums[t]:0;
  s[t]=v; __syncthreads();
  for (int off=1; off<1024; off<<=1){
    int x=(t>=off)? s[t-off]:0; __syncthreads(); s[t]+=x; __syncthreads();
  }
  if (t<nb) bsums[t] = s[t]-v;
}

// P3: LDS counting-sort by bucket; global offsets = S[idx]+bsums[idx>>12] (scan3 folded in)
__global__ __launch_bounds__(256) void k_bscatter(const int* __restrict__ ei,
    const float* __restrict__ ew, const int* __restrict__ S,
    const int* __restrict__ bsums, const int* __restrict__ Gm,
    unsigned int* __restrict__ btmpP, unsigned char* __restrict__ btmpD){
  int l = blockIdx.x / NBLK, b = blockIdx.x - l*NBLK;
  int t = threadIdx.x;
  __shared__ int bstart[NBUK], cur[NBUK], runb[NBUK];
  __shared__ int ps[256];
  __shared__ unsigned int  ebP[CH];     // 16 KB: src16|halfw16
  __shared__ unsigned short ebM[CH];    // 8 KB:  dlow8|buk8
  const int4*   srcs = (const int4*)(ei + (size_t)(2*l)*EE + b*CH);
  const int4*   dsts = (const int4*)(ei + (size_t)(2*l+1)*EE + b*CH);
  const float4* wsrc = (const float4*)(ew + (size_t)l*EE + b*CH);
  int4 sv[4], dv[4]; float4 wv[4];
  #pragma unroll
  for (int i=0;i<4;i++){
    int k4 = t + i*256;
    if (k4<CH4){
      sv[i] = srcs[k4];
      dv[i] = dsts[k4];
      wv[i] = wsrc[k4];
    }
  }
  int v = (t<NBUK)? Gm[(size_t)(l*NBLK+b)*GMS + t] : 0;
  ps[t]=v; __syncthreads();
  for (int o=1;o<256;o<<=1){ int x=(t>=o)?ps[t-o]:0; __syncthreads(); ps[t]+=x; __syncthreads(); }
  if (t<NBUK){
    bstart[t]=ps[t]-v; cur[t]=ps[t]-v;
    int sidx = (l*NBUK+t)*NBLK + b;
    runb[t] = S[sidx] + bsums[sidx>>12];
  }
  __syncthreads();
  #define PUTE(SRC,DST,WF) { int buk=(DST)>>8; int pos=atomicAdd(&cur[buk],1); \
    unsigned short hw=__half_as_ushort(__float2half(WF)); \
    ebP[pos]=(unsigned)(SRC)|((unsigned)hw<<16); \
    ebM[pos]=(unsigned short)(((DST)&255)|(buk<<8)); }
  #pragma unroll
  for (int i=0;i<4;i++){
    int k4 = t + i*256;
    if (k4<CH4){
      PUTE(sv[i].x, dv[i].x, wv[i].x);
      PUTE(sv[i].y, dv[i].y, wv[i].y);
      PUTE(sv[i].z, dv[i].z, wv[i].z);
      PUTE(sv[i].w, dv[i].w, wv[i].w);
    }
  }
  #undef PUTE
  __syncthreads();
  for (int k=t;k<CH;k+=256){
    unsigned short m = ebM[k];
    int buk = m>>8;
    int gp = runb[buk] + (k - bstart[buk]);
    btmpP[gp] = ebP[k];
    btmpD[gp] = (unsigned char)(m&255);
  }
}

// P4: per-bucket count+scan; scatter staged through LDS for coalesced writeback.
__global__ __launch_bounds__(256) void k_fsort(const unsigned int* __restrict__ btmpP,
    const unsigned char* __restrict__ btmpD, const int* __restrict__ S,
    const int* __restrict__ bsums,
    unsigned int* __restrict__ sedge, int* __restrict__ offs){
  int lbuk = blockIdx.x;
  int l = lbuk/NBUK, bl = lbuk - l*NBUK;
  int t = threadIdx.x;
  int i0 = lbuk*NBLK, i1 = i0+NBLK;
  int base = S[i0] + bsums[i0>>12];
  int end  = (i1==SCN)? LE : (S[i1] + bsums[i1>>12]);
  int nE = end - base;
  __shared__ int cnt[256], sc[256];
  __shared__ unsigned int stg[FSCAP];
  cnt[t]=0;
  __syncthreads();
  for (int k=t; k<nE; k+=256) atomicAdd(&cnt[btmpD[base+k]], 1);
  __syncthreads();
  int c = cnt[t];
  sc[t]=c;
  __syncthreads();
  for (int o=1;o<256;o<<=1){
    int v = (t>=o)? sc[t-o]:0;
    __syncthreads();
    sc[t]+=v;
    __syncthreads();
  }
  int excl = sc[t]-c;
  {
    int node = bl*256+t;
    if (node<NN) offs[(size_t)l*NN+node] = base + excl;
  }
  if (lbuk==0 && t==255) offs[LN]=LE;
  if (nE <= FSCAP){
    cnt[t] = excl;                 // LDS-relative running cursor
    __syncthreads();
    for (int k=t; k<nE; k+=256){
      int d = btmpD[base+k];
      int r = atomicAdd(&cnt[d],1);
      stg[r] = btmpP[base+k];
    }
    __syncthreads();
    for (int k=t; k<nE; k+=256) sedge[base+k] = stg[k];   // coalesced writeback
  } else {
    cnt[t] = base + excl;          // fallback: direct global scatter
    __syncthreads();
    for (int k=t; k<nE; k+=256){
      int d = btmpD[base+k];
      int r = atomicAdd(&cnt[d],1);
      sedge[r] = btmpP[base+k];
    }
  }
}

// -------- MFMA GEMM layer 0 (32-row tiles): gather emb, write xbf, compute sup --------
__global__ __launch_bounds__(256) void k_gemm_sup_emb(const int* __restrict__ verts,
    const float* __restrict__ emb, const unsigned short* __restrict__ Wt,
    unsigned short* __restrict__ Y, unsigned short* __restrict__ xout, int M){
  __shared__ unsigned short Xs[32*LSTRIDE];
  int tid = threadIdx.x;
  int row0 = blockIdx.x*32;
  #pragma unroll
  for (int it=0; it<2; it++){
    int idx = tid + it*256;
    int r = idx>>4, k8 = idx&15;
    short8 w = short8(0);
    if (row0+r < M){
      int v = verts[row0+r];
      const float4* p = (const float4*)emb + (size_t)v*32 + k8*2;
      float4 v0 = p[0], v1 = p[1];
      w[0]=(short)f2bf(v0.x); w[1]=(short)f2bf(v0.y); w[2]=(short)f2bf(v0.z); w[3]=(short)f2bf(v0.w);
      w[4]=(short)f2bf(v1.x); w[5]=(short)f2bf(v1.y); w[6]=(short)f2bf(v1.z); w[7]=(short)f2bf(v1.w);
      *(short8*)(xout + (size_t)(row0+r)*128 + k8*8) = w;
    }
    *(short8*)&Xs[r*LSTRIDE + k8*8] = w;
  }
  __syncthreads();
  int w = tid>>6, lane = tid&63, m = lane&15, q = lane>>4;
  int rw = (w&1)*16, cw = (w>>1)*64;
  f32x4 acc[4];
  #pragma unroll
  for (int nt=0;nt<4;nt++){ acc[nt][0]=0.f; acc[nt][1]=0.f; acc[nt][2]=0.f; acc[nt][3]=0.f; }
  #pragma unroll
  for (int kc=0; kc<4; kc++){
    short8 a = *(const short8*)&Xs[(rw+m)*LSTRIDE + kc*32 + 8*q];
    #pragma unroll
    for (int nt=0; nt<4; nt++){
      short8 b = *(const short8*)&Wt[(size_t)(cw+nt*16+m)*128 + kc*32 + 8*q];
      acc[nt] = __builtin_amdgcn_mfma_f32_16x16x32_bf16(a, b, acc[nt], 0,0,0);
    }
  }
  #pragma unroll
  for (int nt=0; nt<4; nt++){
    #pragma unroll
    for (int i=0;i<4;i++){
      int rr = row0 + rw + 4*q + i;
      if (rr<M) Y[(size_t)rr*128 + cw + nt*16 + m] = f2bf(acc[nt][i]);
    }
  }
}

// ------- fused gate, 64-row tiles; FUSE=1: next-layer sup; FUSE=2: output GEMM (bf16 [NN][32]) -------
template<int FUSE>
__global__ __launch_bounds__(256,4) void k_gemm_gate2(const unsigned short* __restrict__ H,
    const float* __restrict__ stL,            // NREP replicas [rep][sum128|sq128]
    const float* __restrict__ gamma, const float* __restrict__ beta,
    const unsigned short* __restrict__ Wl, const unsigned short* __restrict__ Wc,
    const unsigned short* __restrict__ Wn, const float* __restrict__ teb,
    unsigned short* __restrict__ x, unsigned short* __restrict__ supY, int M){
  __shared__ unsigned short XsX[64*LSTRIDE];
  __shared__ unsigned short XsH[64*LSTRIDE];
  __shared__ float sSt[256];
  int tid = threadIdx.x;
  int row0 = blockIdx.x*64;
  int k8 = tid&15;   // feature chunk, same for all 4 row-quarters
  // front-load ALL global reads before any barrier
  float4 g0 = *(const float4*)(gamma + k8*8), g1 = *(const float4*)(gamma + k8*8 + 4);
  float4 b0 = *(const float4*)(beta  + k8*8), b1 = *(const float4*)(beta  + k8*8 + 4);
  short8 xv[4], hv[4];
  #pragma unroll
  for (int it=0; it<4; it++){
    int r = (tid + it*256)>>4;
    xv[it] = short8(0); hv[it] = short8(0);
    if (row0+r < M){
      xv[it] = *(const short8*)(x + (size_t)(row0+r)*128 + k8*8);
      hv[it] = *(const short8*)(H + (size_t)(row0+r)*128 + k8*8);
    }
  }
  // split replica-reduce: 256 threads, one stat slot each (64 loads/thread)
  {
    float sacc = 0.f;
    #pragma unroll 8
    for (int g=0; g<NREP; g++) sacc += stL[g*256 + tid];
    sSt[tid] = sacc;
  }
  #pragma unroll
  for (int it=0; it<4; it++){
    int r = (tid + it*256)>>4;
    *(short8*)&XsX[r*LSTRIDE + k8*8] = xv[it];
  }
  __syncthreads();
  // per-thread BN scale/offset for its 8 features
  float scv[8], ofv[8];
  {
    const float gam[8] = {g0.x,g0.y,g0.z,g0.w,g1.x,g1.y,g1.z,g1.w};
    const float bet[8] = {b0.x,b0.y,b0.z,b0.w,b1.x,b1.y,b1.z,b1.w};
    #pragma unroll
    for (int j=0;j<8;j++){
      float s  = sSt[k8*8+j];
      float sq = sSt[128 + k8*8+j];
      float mean = s*(1.0f/NN);
      float var  = sq*(1.0f/NN) - mean*mean;
      float r = rsqrtf(var+BN_EPS)*gam[j];
      scv[j]=r; ofv[j]=bet[j]-mean*r;
    }
  }
  #pragma unroll
  for (int it=0; it<4; it++){
    int r = (tid + it*256)>>4;
    short8 w;
    #pragma unroll
    for (int j=0;j<8;j++){
      float o = bf2f((unsigned short)hv[it][j]);
      w[j] = (short)f2bf(fmaxf(fmaf(o, scv[j], ofv[j]), 0.f));
    }
    *(short8*)&XsH[r*LSTRIDE + k8*8] = w;
  }
  __syncthreads();
  int w = tid>>6, lane = tid&63, m = lane&15, q = lane>>4;
  int rw = (w>>1)*16, cw = (w&1)*64;   // rows {rw..rw+15, rw+32..rw+47}, cols cw..cw+63
  f32x4 acc[2][4];
  #pragma unroll
  for (int rt=0;rt<2;rt++)
    #pragma unroll
    for (int nt=0;nt<4;nt++){ acc[rt][nt][0]=0.f; acc[rt][nt][1]=0.f; acc[rt][nt][2]=0.f; acc[rt][nt][3]=0.f; }
  #pragma unroll
  for (int kc=0; kc<4; kc++){
    short8 a0 = *(const short8*)&XsX[(rw+m)*LSTRIDE + kc*32 + 8*q];
    short8 a1 = *(const short8*)&XsX[(rw+32+m)*LSTRIDE + kc*32 + 8*q];
    #pragma unroll
    for (int nt=0; nt<4; nt++){
      short8 b = *(const short8*)&Wl[(size_t)(cw+nt*16+m)*128 + kc*32 + 8*q];
      acc[0][nt] = __builtin_amdgcn_mfma_f32_16x16x32_bf16(a0, b, acc[0][nt], 0,0,0);
      acc[1][nt] = __builtin_amdgcn_mfma_f32_16x16x32_bf16(a1, b, acc[1][nt], 0,0,0);
    }
  }
  #pragma unroll
  for (int kc=0; kc<4; kc++){
    short8 a0 = *(const short8*)&XsH[(rw+m)*LSTRIDE + kc*32 + 8*q];
    short8 a1 = *(const short8*)&XsH[(rw+32+m)*LSTRIDE + kc*32 + 8*q];
    #pragma unroll
    for (int nt=0; nt<4; nt++){
      short8 b = *(const short8*)&Wc[(size_t)(cw+nt*16+m)*128 + kc*32 + 8*q];
      acc[0][nt] = __builtin_amdgcn_mfma_f32_16x16x32_bf16(a0, b, acc[0][nt], 0,0,0);
      acc[1][nt] = __builtin_amdgcn_mfma_f32_16x16x32_bf16(a1, b, acc[1][nt], 0,0,0);
    }
  }
  __syncthreads();   // all MFMA A-reads done before epilogue overwrites LDS (race fix)
  // gate epilogue: each (lr,col) cell owned by exactly one thread
  #pragma unroll
  for (int rt=0; rt<2; rt++){
    #pragma unroll
    for (int nt=0; nt<4; nt++){
      int col = cw + nt*16 + m;
      float bias = teb[col];
      #pragma unroll
      for (int i=0;i<4;i++){
        int lr = rw + rt*32 + 4*q + i;
        float hvv = bf2f(XsH[lr*LSTRIDE + col]);
        float xo  = bf2f(XsX[lr*LSTRIDE + col]);
        float g = sigm(acc[rt][nt][i] + bias);
        unsigned short xnb = f2bf(g*hvv + (1.f-g)*xo);
        XsH[lr*LSTRIDE + col] = xnb;
        if (FUSE==1) XsX[lr*LSTRIDE + col] = xnb;
      }
    }
  }
  __syncthreads();
  // coalesced short8 writeback of x_new
  #pragma unroll
  for (int it=0; it<4; it++){
    int r = (tid + it*256)>>4;
    if (row0+r < M)
      *(short8*)(x + (size_t)(row0+r)*128 + k8*8) = *(short8*)&XsH[r*LSTRIDE + k8*8];
  }
  if (FUSE==1){
    #pragma unroll
    for (int rt=0;rt<2;rt++)
      #pragma unroll
      for (int nt=0;nt<4;nt++){ acc[rt][nt][0]=0.f; acc[rt][nt][1]=0.f; acc[rt][nt][2]=0.f; acc[rt][nt][3]=0.f; }
    #pragma unroll
    for (int kc=0; kc<4; kc++){
      short8 a0 = *(const short8*)&XsX[(rw+m)*LSTRIDE + kc*32 + 8*q];
      short8 a1 = *(const short8*)&XsX[(rw+32+m)*LSTRIDE + kc*32 + 8*q];
      #pragma unroll
      for (int nt=0; nt<4; nt++){
        short8 b = *(const short8*)&Wn[(size_t)(cw+nt*16+m)*128 + kc*32 + 8*q];
        acc[0][nt] = __builtin_amdgcn_mfma_f32_16x16x32_bf16(a0, b, acc[0][nt], 0,0,0);
        acc[1][nt] = __builtin_amdgcn_mfma_f32_16x16x32_bf16(a1, b, acc[1][nt], 0,0,0);
      }
    }
    #pragma unroll
    for (int rt=0; rt<2; rt++){
      #pragma unroll
      for (int nt=0; nt<4; nt++){
        #pragma unroll
        for (int i=0;i<4;i++){
          int rr = row0 + rw + rt*32 + 4*q + i;
          if (rr<M) supY[(size_t)rr*128 + cw + nt*16 + m] = f2bf(acc[rt][nt][i]);
        }
      }
    }
  }
  if (FUSE==2){
    // output GEMM: xnew (XsH) @ WtOut -> bf16 supY[NN][32]; waves with cw==0 only
    if (cw==0){
      f32x4 ao0[2], ao1[2];
      #pragma unroll
      for (int nt=0;nt<2;nt++){
        ao0[nt][0]=0.f; ao0[nt][1]=0.f; ao0[nt][2]=0.f; ao0[nt][3]=0.f;
        ao1[nt][0]=0.f; ao1[nt][1]=0.f; ao1[nt][2]=0.f; ao1[nt][3]=0.f;
      }
      #pragma unroll
      for (int kc=0; kc<4; kc++){
        short8 a0 = *(const short8*)&XsH[(rw+m)*LSTRIDE + kc*32 + 8*q];
        short8 a1 = *(const short8*)&XsH[(rw+32+m)*LSTRIDE + kc*32 + 8*q];
        #pragma unroll
        for (int nt=0; nt<2; nt++){
          short8 b = *(const short8*)&Wn[(size_t)(nt*16+m)*128 + kc*32 + 8*q];
          ao0[nt] = __builtin_amdgcn_mfma_f32_16x16x32_bf16(a0, b, ao0[nt], 0,0,0);
          ao1[nt] = __builtin_amdgcn_mfma_f32_16x16x32_bf16(a1, b, ao1[nt], 0,0,0);
        }
      }
      #pragma unroll
      for (int rt=0; rt<2; rt++){
        #pragma unroll
        for (int nt=0; nt<2; nt++){
          #pragma unroll
          for (int i=0;i<4;i++){
            int rr = row0 + rw + rt*32 + 4*q + i;
            float v = rt? ao1[nt][i] : ao0[nt][i];
            if (rr<M) supY[(size_t)rr*32 + nt*16 + m] = f2bf(v);
          }
        }
      }
    }
  }
}

// -------- SpMM gather (contiguous per-node edges, 8-deep unroll) + fused BN stats --------
// (exact round-2 body: do NOT add tail code here — it wrecks regalloc of the gather loop)
__global__ __launch_bounds__(256) void k_spmm128(const unsigned short* __restrict__ sup,
    const unsigned int* __restrict__ sedge, const int* __restrict__ offs,
    unsigned short* __restrict__ h, int lbase, float* __restrict__ stL){
  int nl = threadIdx.x>>5;
  int node = blockIdx.x*8 + nl;
  int fq = threadIdx.x & 31;
  int p = offs[lbase+node], end = offs[lbase+node+1];
  float4 a0 = make_float4(0.f,0.f,0.f,0.f), a1 = a0, a2 = a0, a3 = a0;
  for (; p+7<end; p+=8){
    unsigned int ev[8];
    #pragma unroll
    for (int u=0;u<8;u++) ev[u] = __builtin_nontemporal_load(sedge+p+u);
    ushort4 sv[8];
    #pragma unroll
    for (int u=0;u<8;u++) sv[u] = *(const ushort4*)(sup + (size_t)(ev[u]&0xFFFFu)*128 + fq*4);
    #pragma unroll
    for (int u=0;u<8;u++){
      float w = __half2float(__ushort_as_half((unsigned short)(ev[u]>>16)));
      float4& a = (u&3)==0? a0 : (u&3)==1? a1 : (u&3)==2? a2 : a3;
      a.x += w*bf2f(sv[u].x); a.y += w*bf2f(sv[u].y);
      a.z += w*bf2f(sv[u].z); a.w += w*bf2f(sv[u].w);
    }
  }
  for (; p+3<end; p+=4){
    unsigned int e0 = __builtin_nontemporal_load(sedge+p);
    unsigned int e1 = __builtin_nontemporal_load(sedge+p+1);
    unsigned int e2 = __builtin_nontemporal_load(sedge+p+2);
    unsigned int e3 = __builtin_nontemporal_load(sedge+p+3);
    ushort4 s0 = *(const ushort4*)(sup + (size_t)(e0&0xFFFFu)*128 + fq*4);
    ushort4 s1 = *(const ushort4*)(sup + (size_t)(e1&0xFFFFu)*128 + fq*4);
    ushort4 s2 = *(const ushort4*)(sup + (size_t)(e2&0xFFFFu)*128 + fq*4);
    ushort4 s3 = *(const ushort4*)(sup + (size_t)(e3&0xFFFFu)*128 + fq*4);
    float w0 = __half2float(__ushort_as_half((unsigned short)(e0>>16)));
    float w1 = __half2float(__ushort_as_half((unsigned short)(e1>>16)));
    float w2 = __half2float(__ushort_as_half((unsigned short)(e2>>16)));
    float w3 = __half2float(__ushort_as_half((unsigned short)(e3>>16)));
    a0.x += w0*bf2f(s0.x); a0.y += w0*bf2f(s0.y); a0.z += w0*bf2f(s0.z); a0.w += w0*bf2f(s0.w);
    a1.x += w1*bf2f(s1.x); a1.y += w1*bf2f(s1.y); a1.z += w1*bf2f(s1.z); a1.w += w1*bf2f(s1.w);
    a2.x += w2*bf2f(s2.x); a2.y += w2*bf2f(s2.y); a2.z += w2*bf2f(s2.z); a2.w += w2*bf2f(s2.w);
    a3.x += w3*bf2f(s3.x); a3.y += w3*bf2f(s3.y); a3.z += w3*bf2f(s3.z); a3.w += w3*bf2f(s3.w);
  }
  for (; p<end; p++){
    unsigned int e0 = __builtin_nontemporal_load(sedge+p);
    float w0 = __half2float(__ushort_as_half((unsigned short)(e0>>16)));
    ushort4 s0 = *(const ushort4*)(sup + (size_t)(e0&0xFFFFu)*128 + fq*4);
    a0.x += w0*bf2f(s0.x); a0.y += w0*bf2f(s0.y); a0.z += w0*bf2f(s0.z); a0.w += w0*bf2f(s0.w);
  }
  a0.x+=a1.x+a2.x+a3.x; a0.y+=a1.y+a2.y+a3.y;
  a0.z+=a1.z+a2.z+a3.z; a0.w+=a1.w+a2.w+a3.w;
  ushort4 ov;
  ov.x=f2bf(a0.x); ov.y=f2bf(a0.y); ov.z=f2bf(a0.z); ov.w=f2bf(a0.w);
  *(ushort4*)(h + (size_t)node*128 + fq*4) = ov;
  __shared__ float sP[8][132], sQ[8][132];
  int f0 = fq*4;
  sP[nl][f0+0]=a0.x; sP[nl][f0+1]=a0.y; sP[nl][f0+2]=a0.z; sP[nl][f0+3]=a0.w;
  sQ[nl][f0+0]=a0.x*a0.x; sQ[nl][f0+1]=a0.y*a0.y; sQ[nl][f0+2]=a0.z*a0.z; sQ[nl][f0+3]=a0.w*a0.w;
  __syncthreads();
  if (threadIdx.x < 128){
    int f = threadIdx.x;
    float s=0.f, sq=0.f;
    #pragma unroll
    for (int n=0;n<8;n++){ s += sP[n][f]; sq += sQ[n][f]; }
    float* base = stL + (blockIdx.x & (NREP-1))*256;
    atomicAdd(&base[f], s); atomicAdd(&base[128+f], sq);
  }
}

// -------- output SpMM: bf16 [NN][32] sup rows, one cacheline/edge; fused BN stats tail --------
__global__ __launch_bounds__(256) void k_spmm_out(const unsigned short* __restrict__ sup,
    const unsigned int* __restrict__ sedge, const int* __restrict__ offs,
    float* __restrict__ h, int lbase, float* __restrict__ st8){
  int nl = threadIdx.x>>5;
  int node = blockIdx.x*8 + nl;
  int c = threadIdx.x & 31;
  bool act = c < OUTC;
  int p = offs[lbase+node], end = offs[lbase+node+1];
  float a0=0.f,a1=0.f,a2=0.f,a3=0.f;
  for (; p+7<end; p+=8){
    unsigned int ev[8];
    #pragma unroll
    for (int u=0;u<8;u++) ev[u] = __builtin_nontemporal_load(sedge+p+u);
    float sv[8];
    #pragma unroll
    for (int u=0;u<8;u++) sv[u] = bf2f(sup[(size_t)(ev[u]&0xFFFFu)*32 + c]);
    #pragma unroll
    for (int u=0;u<8;u++){
      float w = __half2float(__ushort_as_half((unsigned short)(ev[u]>>16)));
      if ((u&3)==0) a0 += w*sv[u];
      else if ((u&3)==1) a1 += w*sv[u];
      else if ((u&3)==2) a2 += w*sv[u];
      else a3 += w*sv[u];
    }
  }
  for (; p<end; p++){
    unsigned int e = __builtin_nontemporal_load(sedge+p);
    float w = __half2float(__ushort_as_half((unsigned short)(e>>16)));
    a0 += w*bf2f(sup[(size_t)(e&0xFFFFu)*32 + c]);
  }
  float v = a0+a1+a2+a3;
  if (act) h[(size_t)node*OUTC+c] = v;
  if (!act) v = 0.f;
  __shared__ float sS[8][33], sQ[8][33];
  sS[nl][c] = v; sQ[nl][c] = v*v;
  __syncthreads();
  if (threadIdx.x < 32){
    float s=0.f, sq=0.f;
    #pragma unroll
    for (int n=0;n<8;n++){ s += sS[n][c]; sq += sQ[n][c]; }
    if (c<OUTC){
      float* base = st8 + (blockIdx.x&7)*64;
      atomicAdd(&base[c], s); atomicAdd(&base[32+c], sq);
    }
  }
}

// ---------- fused: BN-normalize+ReLU inline + masked reduce (8-way replicated) ----------
__global__ __launch_bounds__(256) void k_reduce(const float* __restrict__ xf,
    const float* __restrict__ st8, const float* __restrict__ gamma,
    const float* __restrict__ beta, const int* __restrict__ verts,
    const float* __restrict__ mw, float* __restrict__ acc8, int rpb){
  int c = threadIdx.x & 31, g = threadIdx.x >> 5;
  float scn=0.f, offc=0.f;
  if (c<OUTC){
    float s=0.f, sq=0.f;
    #pragma unroll
    for (int i=0;i<8;i++){ s += st8[i*64+c]; sq += st8[i*64+32+c]; }
    const float invN = 1.0f/NN;
    float m = s*invN;
    float var = sq*invN - m*m;
    scn = rsqrtf(var+BN_EPS)*gamma[c];
    offc = beta[c] - m*scn;
  }
  int r0 = blockIdx.x*rpb;
  int r1 = min(NN, r0+rpb);
  float s=0.f;
  for (int r=r0+g; r<r1; r+=8){
    float m = mw[verts[r]];
    if (c<OUTC){
      float v = fmaxf(fmaf(xf[(size_t)r*OUTC+c], scn, offc), 0.f);
      s += m * v;
    }
  }
  __shared__ float sh[256];
  sh[threadIdx.x]=s; __syncthreads();
  if (threadIdx.x<32){
    #pragma unroll
    for (int i=1;i<8;i++) s += sh[threadIdx.x + i*32];
    if (c<OUTC) atomicAdd(&acc8[(blockIdx.x&7)*32 + c], s);
  }
}

__global__ void k_final(const float* __restrict__ acc8, const float* __restrict__ mb,
                        float* __restrict__ out){
  int c=threadIdx.x;
  if (c<OUTC){
    float s=0.f;
    #pragma unroll
    for (int g=0; g<8; g++) s += acc8[g*32+c];
    out[c] = sigm(s+mb[c]);
  }
}

// ---------------- host ----------------
extern "C" void kernel_launch(void* const* d_in, const int* in_sizes, int n_in,
                              void* d_out, int out_size, void* d_ws, size_t ws_size,
                              hipStream_t stream){
  const int*   verts = (const int*)d_in[0];
  const int*   ei    = (const int*)d_in[1];
  const float* ew    = (const float*)d_in[2];
  const float* emb   = (const float*)d_in[3];
  const float* wh    = (const float*)d_in[4];
  const float* w_out = (const float*)d_in[6];
  const float* bng_h = (const float*)d_in[8];
  const float* bnb_h = (const float*)d_in[9];
  const float* bng_o = (const float*)d_in[10];
  const float* bnb_o = (const float*)d_in[11];
  const float* tewl  = (const float*)d_in[12];
  const float* tewc  = (const float*)d_in[13];
  const float* teb   = (const float*)d_in[14];
  const float* maskw = (const float*)d_in[15];
  const float* maskb = (const float*)d_in[16];
  float* out = (float*)d_out;

  char* ws = (char*)d_ws;
  size_t off=0;
  auto alloc=[&](size_t bytes)->char*{ char* p = ws+off; off += (bytes+255)&~(size_t)255; return p; };
  unsigned int* sedge = (unsigned int*)alloc(sizeof(int)*LE);   // 22.4 MB
  int*   offs   = (int*)  alloc(sizeof(int)*(LN+1));            // 1.4 MB
  int*   Gm     = (int*)  alloc(sizeof(int)*LL*NBLK*GMS);       // 1.1 MB
  int*   S      = (int*)  alloc(sizeof(int)*(SCN+1));           // 1.1 MB
  int*   bsums  = (int*)  alloc(sizeof(int)*1024);
  unsigned short* xbf   = (unsigned short*)alloc(sizeof(short)*NN*DIM); // 12.8 MB
  unsigned short* supbf = (unsigned short*)alloc(sizeof(short)*NN*DIM); // 12.8 MB
  unsigned short* hbf   = (unsigned short*)alloc(sizeof(short)*NN*DIM); // 12.8 MB
  unsigned short* supO  = (unsigned short*)alloc(sizeof(short)*NN*32);  // 3.2 MB bf16 [NN][32]
  unsigned short* Wt = (unsigned short*)alloc(sizeof(short)*18*DIM*DIM);
  unsigned short* WtO = (unsigned short*)alloc(sizeof(short)*32*DIM);   // 8 KB
  float* stats  = (float*)alloc(sizeof(float)*STATSZ);
  float* ostat8 = stats + 6*NREP*256;  // [8][64]
  float* racc8  = ostat8 + 8*64;       // [8][32]
  unsigned int*  btmpP = (unsigned int*)xbf;
  unsigned char* btmpD = (unsigned char*)hbf;

  // --- fused prologue + LDS-atomic counting sort (scan3 folded into consumers) ---
  k_pre<<<2665,256,0,stream>>>(wh, tewl, tewc, w_out, Wt, WtO, ei, Gm, stats);
  int nsb = (SCN+4095)/4096;  // 68
  k_scan1p<<<nsb,256,0,stream>>>(Gm, S, bsums);
  k_scan2<<<1,1024,0,stream>>>(bsums, nsb);
  k_bscatter<<<LL*NBLK,256,0,stream>>>(ei, ew, S, bsums, Gm, btmpP, btmpD);
  k_fsort<<<LL*NBUK,256,0,stream>>>(btmpP, btmpD, S, bsums, sedge, offs);

  // --- 6 hidden layers; sup for layer i+1 (or output) computed inside gate2 of layer i ---
  k_gemm_sup_emb<<<(NN+31)/32,256,0,stream>>>(verts, emb, Wt, supbf, xbf, NN);
  for (int i=0;i<6;i++){
    int j = (i==0)?5:(i-1);
    float* stL = stats + i*NREP*256;
    k_spmm128<<<NN/8,256,0,stream>>>(supbf, sedge, offs, hbf, i*NN, stL);
    if (i<5)
      k_gemm_gate2<1><<<(NN+63)/64,256,0,stream>>>(hbf, stL,
          bng_h+(size_t)i*DIM, bnb_h+(size_t)i*DIM,
          Wt + (size_t)(6+j)*DIM*DIM, Wt + (size_t)(12+j)*DIM*DIM,
          Wt + (size_t)(i+1)*DIM*DIM, teb + (size_t)j*DIM, xbf, supbf, NN);
    else
      k_gemm_gate2<2><<<(NN+63)/64,256,0,stream>>>(hbf, stL,
          bng_h+(size_t)i*DIM, bnb_h+(size_t)i*DIM,
          Wt + (size_t)(6+j)*DIM*DIM, Wt + (size_t)(12+j)*DIM*DIM,
          WtO, teb + (size_t)j*DIM, xbf, supO, NN);
  }

  // --- output layer: spmm on bf16 [NN][32] sup; fp32 h + fused stats ---
  k_spmm_out<<<NN/8,256,0,stream>>>(supO, sedge, offs, (float*)hbf, 6*NN, ostat8);
  float* bufO = (float*)hbf;
  k_reduce<<<512,256,0,stream>>>(bufO, ostat8, bng_o, bnb_o, verts, maskw, racc8, 98);
  k_final<<<1,64,0,stream>>>(racc8, maskb, out);
}

// Round 7
// 655.486 us; speedup vs baseline: 4.1631x; 1.0717x over previous
//
#include <hip/hip_runtime.h>
#include <hip/hip_fp16.h>

#define NN 50000
#define EE 800000
#define DIM 128
#define OUTC 20
#define LL 7
#define LE (LL*EE)
#define LN (LL*NN)
#define BN_EPS 1e-5f
#define LSTRIDE 136     // bf16 elems per LDS row
#define NREP 64         // BN stat replicas
#define NBUK 196        // coarse buckets of 256 dsts per layer
#define GMS  200        // padded Gm stride
#define NBLK 200        // edge-blocks per layer (EE/NBLK = 4000)
#define CH   4000
#define CH4  (CH/4)
#define SCN  (LL*NBUK*NBLK)   // 274400 scan entries
#define FSCAP 4864      // fsort LDS staging capacity
#define STATSZ (6*NREP*256 + 8*64 + 8*32 + 8)   // stats + ostat8 + racc8 + tick
#define STATSZ4 (STATSZ/4)

typedef __attribute__((ext_vector_type(8))) short short8;
typedef __attribute__((ext_vector_type(4))) float f32x4;

static __device__ __forceinline__ float sigm(float z){ return 1.0f/(1.0f+expf(-z)); }
static __device__ __forceinline__ unsigned short f2bf(float f){
  unsigned int u = __float_as_uint(f);
  u += 0x7FFF + ((u>>16)&1);            // RNE
  return (unsigned short)(u>>16);
}
static __device__ __forceinline__ float bf2f(unsigned short s){
  return __uint_as_float(((unsigned int)s)<<16);
}

// ======== fused prologue: weight transpose+cvt, dst histogram, stats zero ========
// blocks [0,1152): Wt transpose; [1152,1168): WtOut; [1168,2568): bh; [2568,2665): zero stats
__global__ __launch_bounds__(256) void k_pre(const float* __restrict__ wh,
    const float* __restrict__ tewl, const float* __restrict__ tewc,
    const float* __restrict__ wout,
    unsigned short* __restrict__ Wt, unsigned short* __restrict__ WtO,
    const int* __restrict__ ei, int* __restrict__ Gm, float* __restrict__ stats){
  int bid = blockIdx.x;
  int t = threadIdx.x;
  if (bid < 1152){
    int gid = bid*256+t;
    int m = gid>>14; int idx = gid&16383;
    int n = idx>>7, k = idx&127;
    const float* src = (m<6)? wh + (size_t)m*16384
                     : (m<12)? tewl + (size_t)(m-6)*16384
                     : tewc + (size_t)(m-12)*16384;
    Wt[gid] = f2bf(src[k*128+n]);
  } else if (bid < 1168){
    int idx = (bid-1152)*256+t;       // 0..4095 over [32][128]
    int n = idx>>7, k = idx&127;
    WtO[idx] = (n<OUTC)? f2bf(wout[k*OUTC+n]) : (unsigned short)0;
  } else if (bid < 2568){
    int bb = bid-1168;
    int l = bb / NBLK, b = bb - l*NBLK;
    __shared__ int h[NBUK];
    if (t<NBUK) h[t]=0;
    const int4* dsts = (const int4*)(ei + (size_t)(2*l+1)*EE + b*CH);
    int4 dv[4];
    #pragma unroll
    for (int i=0;i<4;i++){
      int k4 = t + i*256;
      if (k4<CH4) dv[i] = dsts[k4];
    }
    __syncthreads();
    #pragma unroll
    for (int i=0;i<4;i++){
      int k4 = t + i*256;
      if (k4<CH4){
        atomicAdd(&h[dv[i].x>>8], 1);
        atomicAdd(&h[dv[i].y>>8], 1);
        atomicAdd(&h[dv[i].z>>8], 1);
        atomicAdd(&h[dv[i].w>>8], 1);
      }
    }
    __syncthreads();
    int* g = Gm + (size_t)(l*NBLK+b)*GMS;
    if (t<NBUK) g[t]=h[t];
  } else {
    int z = (bid-2568)*256+t;
    if (z < STATSZ4) ((float4*)stats)[z] = make_float4(0.f,0.f,0.f,0.f);
  }
}

__global__ __launch_bounds__(256) void k_scan1p(const int* __restrict__ Gm,
    int* __restrict__ part, int* __restrict__ bsums){
  __shared__ int s[256];
  int t = threadIdx.x;
  int base = blockIdx.x*4096 + t*16;
  int v[16]; int sum = 0;
  #pragma unroll
  for (int i=0;i<16;i++){
    int idx = base+i; int val = 0;
    if (idx < SCN){
      int l = idx/(NBUK*NBLK);
      int r = idx - l*(NBUK*NBLK);
      int buk = r/NBLK, b = r - buk*NBLK;
      val = Gm[(size_t)(l*NBLK+b)*GMS + buk];
    }
    v[i]=val; sum+=val;
  }
  s[t]=sum; __syncthreads();
  for (int off=1; off<256; off<<=1){
    int x = (t>=off)? s[t-off] : 0;
    __syncthreads(); s[t]+=x; __syncthreads();
  }
  if (t==255) bsums[blockIdx.x] = s[255];
  int run = s[t]-sum;
  #pragma unroll
  for (int i=0;i<16;i++){ if (base+i<SCN) part[base+i]=run; run += v[i]; }
}

__global__ __launch_bounds__(1024) void k_scan2(int* bsums, int nb){
  __shared__ int s[1024];
  int t=threadIdx.x;
  int v = (t<nb)? bsums[t]:0;
  s[t]=v; __syncthreads();
  for (int off=1; off<1024; off<<=1){
    int x=(t>=off)? s[t-off]:0; __syncthreads(); s[t]+=x; __syncthreads();
  }
  if (t<nb) bsums[t] = s[t]-v;
}

// P3: LDS counting-sort by bucket; wave-shuffle scan (2 barriers vs 16)
__global__ __launch_bounds__(256) void k_bscatter(const int* __restrict__ ei,
    const float* __restrict__ ew, const int* __restrict__ S,
    const int* __restrict__ bsums, const int* __restrict__ Gm,
    unsigned int* __restrict__ btmpP, unsigned char* __restrict__ btmpD){
  int l = blockIdx.x / NBLK, b = blockIdx.x - l*NBLK;
  int t = threadIdx.x;
  __shared__ int bstart[NBUK], cur[NBUK], runb[NBUK];
  __shared__ int wsum[4];
  __shared__ unsigned int  ebP[CH];     // 16 KB: src16|halfw16
  __shared__ unsigned short ebM[CH];    // 8 KB:  dlow8|buk8
  const int4*   srcs = (const int4*)(ei + (size_t)(2*l)*EE + b*CH);
  const int4*   dsts = (const int4*)(ei + (size_t)(2*l+1)*EE + b*CH);
  const float4* wsrc = (const float4*)(ew + (size_t)l*EE + b*CH);
  int4 sv[4], dv[4]; float4 wv[4];
  #pragma unroll
  for (int i=0;i<4;i++){
    int k4 = t + i*256;
    if (k4<CH4){
      sv[i] = srcs[k4];
      dv[i] = dsts[k4];
      wv[i] = wsrc[k4];
    }
  }
  int v = (t<NBUK)? Gm[(size_t)(l*NBLK+b)*GMS + t] : 0;
  // wave-level inclusive scan + cross-wave combine
  int incl = v;
  #pragma unroll
  for (int d=1; d<64; d<<=1){
    int n = __shfl_up(incl, d, 64);
    if ((t&63) >= d) incl += n;
  }
  if ((t&63)==63) wsum[t>>6] = incl;
  __syncthreads();
  {
    int wv_ = t>>6, add = 0;
    if (wv_>0) add += wsum[0];
    if (wv_>1) add += wsum[1];
    if (wv_>2) add += wsum[2];
    incl += add;
  }
  if (t<NBUK){
    bstart[t]=incl-v; cur[t]=incl-v;
    int sidx = (l*NBUK+t)*NBLK + b;
    runb[t] = S[sidx] + bsums[sidx>>12];
  }
  __syncthreads();
  #define PUTE(SRC,DST,WF) { int buk=(DST)>>8; int pos=atomicAdd(&cur[buk],1); \
    unsigned short hw=__half_as_ushort(__float2half(WF)); \
    ebP[pos]=(unsigned)(SRC)|((unsigned)hw<<16); \
    ebM[pos]=(unsigned short)(((DST)&255)|(buk<<8)); }
  #pragma unroll
  for (int i=0;i<4;i++){
    int k4 = t + i*256;
    if (k4<CH4){
      PUTE(sv[i].x, dv[i].x, wv[i].x);
      PUTE(sv[i].y, dv[i].y, wv[i].y);
      PUTE(sv[i].z, dv[i].z, wv[i].z);
      PUTE(sv[i].w, dv[i].w, wv[i].w);
    }
  }
  #undef PUTE
  __syncthreads();
  for (int k=t;k<CH;k+=256){
    unsigned short m = ebM[k];
    int buk = m>>8;
    int gp = runb[buk] + (k - bstart[buk]);
    btmpP[gp] = ebP[k];
    btmpD[gp] = (unsigned char)(m&255);
  }
}

// P4: per-bucket count+scan (wave-shuffle); scatter staged through LDS.
__global__ __launch_bounds__(256) void k_fsort(const unsigned int* __restrict__ btmpP,
    const unsigned char* __restrict__ btmpD, const int* __restrict__ S,
    const int* __restrict__ bsums,
    unsigned int* __restrict__ sedge, int* __restrict__ offs){
  int lbuk = blockIdx.x;
  int l = lbuk/NBUK, bl = lbuk - l*NBUK;
  int t = threadIdx.x;
  int i0 = lbuk*NBLK, i1 = i0+NBLK;
  int base = S[i0] + bsums[i0>>12];
  int end  = (i1==SCN)? LE : (S[i1] + bsums[i1>>12]);
  int nE = end - base;
  __shared__ int cnt[256];
  __shared__ int wsum[4];
  __shared__ unsigned int stg[FSCAP];
  cnt[t]=0;
  __syncthreads();
  for (int k=t; k<nE; k+=256) atomicAdd(&cnt[btmpD[base+k]], 1);
  __syncthreads();
  int c = cnt[t];
  int incl = c;
  #pragma unroll
  for (int d=1; d<64; d<<=1){
    int n = __shfl_up(incl, d, 64);
    if ((t&63) >= d) incl += n;
  }
  if ((t&63)==63) wsum[t>>6] = incl;
  __syncthreads();
  {
    int wv_ = t>>6, add = 0;
    if (wv_>0) add += wsum[0];
    if (wv_>1) add += wsum[1];
    if (wv_>2) add += wsum[2];
    incl += add;
  }
  int excl = incl - c;
  {
    int node = bl*256+t;
    if (node<NN) offs[(size_t)l*NN+node] = base + excl;
  }
  if (lbuk==0 && t==255) offs[LN]=LE;
  if (nE <= FSCAP){
    cnt[t] = excl;                 // LDS-relative running cursor
    __syncthreads();
    for (int k=t; k<nE; k+=256){
      int d = btmpD[base+k];
      int r = atomicAdd(&cnt[d],1);
      stg[r] = btmpP[base+k];
    }
    __syncthreads();
    for (int k=t; k<nE; k+=256) sedge[base+k] = stg[k];   // coalesced writeback
  } else {
    cnt[t] = base + excl;          // fallback: direct global scatter
    __syncthreads();
    for (int k=t; k<nE; k+=256){
      int d = btmpD[base+k];
      int r = atomicAdd(&cnt[d],1);
      sedge[r] = btmpP[base+k];
    }
  }
}

// -------- MFMA GEMM layer 0 (32-row tiles): gather emb, write xbf, compute sup --------
__global__ __launch_bounds__(256) void k_gemm_sup_emb(const int* __restrict__ verts,
    const float* __restrict__ emb, const unsigned short* __restrict__ Wt,
    unsigned short* __restrict__ Y, unsigned short* __restrict__ xout, int M){
  __shared__ unsigned short Xs[32*LSTRIDE];
  int tid = threadIdx.x;
  int row0 = blockIdx.x*32;
  #pragma unroll
  for (int it=0; it<2; it++){
    int idx = tid + it*256;
    int r = idx>>4, k8 = idx&15;
    short8 w = short8(0);
    if (row0+r < M){
      int v = verts[row0+r];
      const float4* p = (const float4*)emb + (size_t)v*32 + k8*2;
      float4 v0 = p[0], v1 = p[1];
      w[0]=(short)f2bf(v0.x); w[1]=(short)f2bf(v0.y); w[2]=(short)f2bf(v0.z); w[3]=(short)f2bf(v0.w);
      w[4]=(short)f2bf(v1.x); w[5]=(short)f2bf(v1.y); w[6]=(short)f2bf(v1.z); w[7]=(short)f2bf(v1.w);
      *(short8*)(xout + (size_t)(row0+r)*128 + k8*8) = w;
    }
    *(short8*)&Xs[r*LSTRIDE + k8*8] = w;
  }
  __syncthreads();
  int w = tid>>6, lane = tid&63, m = lane&15, q = lane>>4;
  int rw = (w&1)*16, cw = (w>>1)*64;
  f32x4 acc[4];
  #pragma unroll
  for (int nt=0;nt<4;nt++){ acc[nt][0]=0.f; acc[nt][1]=0.f; acc[nt][2]=0.f; acc[nt][3]=0.f; }
  #pragma unroll
  for (int kc=0; kc<4; kc++){
    short8 a = *(const short8*)&Xs[(rw+m)*LSTRIDE + kc*32 + 8*q];
    #pragma unroll
    for (int nt=0; nt<4; nt++){
      short8 b = *(const short8*)&Wt[(size_t)(cw+nt*16+m)*128 + kc*32 + 8*q];
      acc[nt] = __builtin_amdgcn_mfma_f32_16x16x32_bf16(a, b, acc[nt], 0,0,0);
    }
  }
  #pragma unroll
  for (int nt=0; nt<4; nt++){
    #pragma unroll
    for (int i=0;i<4;i++){
      int rr = row0 + rw + 4*q + i;
      if (rr<M) Y[(size_t)rr*128 + cw + nt*16 + m] = f2bf(acc[nt][i]);
    }
  }
}

// ------- fused gate, 64-row tiles, COLUMN-partitioned waves (each weight read once/block) -------
// FUSE=1: next-layer sup; FUSE=2: output GEMM (bf16 [NN][32])
template<int FUSE>
__global__ __launch_bounds__(256,4) void k_gemm_gate2(const unsigned short* __restrict__ H,
    const float* __restrict__ stL,            // NREP replicas [rep][sum128|sq128]
    const float* __restrict__ gamma, const float* __restrict__ beta,
    const unsigned short* __restrict__ Wl, const unsigned short* __restrict__ Wc,
    const unsigned short* __restrict__ Wn, const float* __restrict__ teb,
    unsigned short* __restrict__ x, unsigned short* __restrict__ supY, int M){
  __shared__ unsigned short XsX[64*LSTRIDE];
  __shared__ unsigned short XsH[64*LSTRIDE];
  __shared__ float sSt[256];
  int tid = threadIdx.x;
  int row0 = blockIdx.x*64;
  int k8 = tid&15;   // feature chunk, same for all 4 row-quarters
  int w = tid>>6, lane = tid&63, m = lane&15, q = lane>>4;
  int cw = w*32;     // each wave owns a 32-col slice
  // front-load ALL global reads before any barrier
  float4 g0 = *(const float4*)(gamma + k8*8), g1 = *(const float4*)(gamma + k8*8 + 4);
  float4 b0v = *(const float4*)(beta  + k8*8), b1v = *(const float4*)(beta  + k8*8 + 4);
  float tb0 = teb[cw+m], tb1 = teb[cw+16+m];
  short8 xv[4], hv[4];
  #pragma unroll
  for (int it=0; it<4; it++){
    int r = (tid + it*256)>>4;
    xv[it] = short8(0); hv[it] = short8(0);
    if (row0+r < M){
      xv[it] = *(const short8*)(x + (size_t)(row0+r)*128 + k8*8);
      hv[it] = *(const short8*)(H + (size_t)(row0+r)*128 + k8*8);
    }
  }
  // split replica-reduce: 256 threads, one stat slot each (64 loads/thread)
  {
    float sacc = 0.f;
    #pragma unroll 8
    for (int g=0; g<NREP; g++) sacc += stL[g*256 + tid];
    sSt[tid] = sacc;
  }
  #pragma unroll
  for (int it=0; it<4; it++){
    int r = (tid + it*256)>>4;
    *(short8*)&XsX[r*LSTRIDE + k8*8] = xv[it];
  }
  __syncthreads();
  // per-thread BN scale/offset for its 8 features
  float scv[8], ofv[8];
  {
    const float gam[8] = {g0.x,g0.y,g0.z,g0.w,g1.x,g1.y,g1.z,g1.w};
    const float bet[8] = {b0v.x,b0v.y,b0v.z,b0v.w,b1v.x,b1v.y,b1v.z,b1v.w};
    #pragma unroll
    for (int j=0;j<8;j++){
      float s  = sSt[k8*8+j];
      float sq = sSt[128 + k8*8+j];
      float mean = s*(1.0f/NN);
      float var  = sq*(1.0f/NN) - mean*mean;
      float r = rsqrtf(var+BN_EPS)*gam[j];
      scv[j]=r; ofv[j]=bet[j]-mean*r;
    }
  }
  #pragma unroll
  for (int it=0; it<4; it++){
    int r = (tid + it*256)>>4;
    short8 wv_;
    #pragma unroll
    for (int j=0;j<8;j++){
      float o = bf2f((unsigned short)hv[it][j]);
      wv_[j] = (short)f2bf(fmaxf(fmaf(o, scv[j], ofv[j]), 0.f));
    }
    *(short8*)&XsH[r*LSTRIDE + k8*8] = wv_;
  }
  __syncthreads();
  f32x4 acc[4][2];
  #pragma unroll
  for (int rt=0;rt<4;rt++)
    #pragma unroll
    for (int nt=0;nt<2;nt++){ acc[rt][nt][0]=0.f; acc[rt][nt][1]=0.f; acc[rt][nt][2]=0.f; acc[rt][nt][3]=0.f; }
  // GEMM1: x @ Wl  — each wave loads only its 32-col slice of Wl (once per block)
  #pragma unroll
  for (int kc=0; kc<4; kc++){
    short8 b0 = *(const short8*)&Wl[(size_t)(cw+m)*128 + kc*32 + 8*q];
    short8 b1 = *(const short8*)&Wl[(size_t)(cw+16+m)*128 + kc*32 + 8*q];
    #pragma unroll
    for (int rt=0; rt<4; rt++){
      short8 a = *(const short8*)&XsX[(rt*16+m)*LSTRIDE + kc*32 + 8*q];
      acc[rt][0] = __builtin_amdgcn_mfma_f32_16x16x32_bf16(a, b0, acc[rt][0], 0,0,0);
      acc[rt][1] = __builtin_amdgcn_mfma_f32_16x16x32_bf16(a, b1, acc[rt][1], 0,0,0);
    }
  }
  // GEMM2: hnorm @ Wc
  #pragma unroll
  for (int kc=0; kc<4; kc++){
    short8 b0 = *(const short8*)&Wc[(size_t)(cw+m)*128 + kc*32 + 8*q];
    short8 b1 = *(const short8*)&Wc[(size_t)(cw+16+m)*128 + kc*32 + 8*q];
    #pragma unroll
    for (int rt=0; rt<4; rt++){
      short8 a = *(const short8*)&XsH[(rt*16+m)*LSTRIDE + kc*32 + 8*q];
      acc[rt][0] = __builtin_amdgcn_mfma_f32_16x16x32_bf16(a, b0, acc[rt][0], 0,0,0);
      acc[rt][1] = __builtin_amdgcn_mfma_f32_16x16x32_bf16(a, b1, acc[rt][1], 0,0,0);
    }
  }
  __syncthreads();   // all MFMA A-reads done before epilogue overwrites LDS
  // gate epilogue: each (lr,col) cell owned by exactly one thread
  #pragma unroll
  for (int rt=0; rt<4; rt++){
    #pragma unroll
    for (int nt=0; nt<2; nt++){
      int col = cw + nt*16 + m;
      float bias = nt? tb1 : tb0;
      #pragma unroll
      for (int i=0;i<4;i++){
        int lr = rt*16 + 4*q + i;
        float hvv = bf2f(XsH[lr*LSTRIDE + col]);
        float xo  = bf2f(XsX[lr*LSTRIDE + col]);
        float g = sigm(acc[rt][nt][i] + bias);
        unsigned short xnb = f2bf(g*hvv + (1.f-g)*xo);
        XsH[lr*LSTRIDE + col] = xnb;
        if (FUSE==1) XsX[lr*LSTRIDE + col] = xnb;
      }
    }
  }
  __syncthreads();
  // coalesced short8 writeback of x_new
  #pragma unroll
  for (int it=0; it<4; it++){
    int r = (tid + it*256)>>4;
    if (row0+r < M)
      *(short8*)(x + (size_t)(row0+r)*128 + k8*8) = *(short8*)&XsH[r*LSTRIDE + k8*8];
  }
  if (FUSE==1){
    #pragma unroll
    for (int rt=0;rt<4;rt++)
      #pragma unroll
      for (int nt=0;nt<2;nt++){ acc[rt][nt][0]=0.f; acc[rt][nt][1]=0.f; acc[rt][nt][2]=0.f; acc[rt][nt][3]=0.f; }
    #pragma unroll
    for (int kc=0; kc<4; kc++){
      short8 b0 = *(const short8*)&Wn[(size_t)(cw+m)*128 + kc*32 + 8*q];
      short8 b1 = *(const short8*)&Wn[(size_t)(cw+16+m)*128 + kc*32 + 8*q];
      #pragma unroll
      for (int rt=0; rt<4; rt++){
        short8 a = *(const short8*)&XsX[(rt*16+m)*LSTRIDE + kc*32 + 8*q];
        acc[rt][0] = __builtin_amdgcn_mfma_f32_16x16x32_bf16(a, b0, acc[rt][0], 0,0,0);
        acc[rt][1] = __builtin_amdgcn_mfma_f32_16x16x32_bf16(a, b1, acc[rt][1], 0,0,0);
      }
    }
    #pragma unroll
    for (int rt=0; rt<4; rt++){
      #pragma unroll
      for (int nt=0; nt<2; nt++){
        #pragma unroll
        for (int i=0;i<4;i++){
          int rr = row0 + rt*16 + 4*q + i;
          if (rr<M) supY[(size_t)rr*128 + cw + nt*16 + m] = f2bf(acc[rt][nt][i]);
        }
      }
    }
  }
  if (FUSE==2){
    // output GEMM: xnew (XsH) @ WtOut -> bf16 supY[NN][32]; waves 0,1 split row-tiles
    if (w < 2){
      f32x4 ao[2][2];
      #pragma unroll
      for (int rt=0;rt<2;rt++)
        #pragma unroll
        for (int nt=0;nt<2;nt++){ ao[rt][nt][0]=0.f; ao[rt][nt][1]=0.f; ao[rt][nt][2]=0.f; ao[rt][nt][3]=0.f; }
      #pragma unroll
      for (int kc=0; kc<4; kc++){
        short8 b0 = *(const short8*)&Wn[(size_t)(m)*128 + kc*32 + 8*q];
        short8 b1 = *(const short8*)&Wn[(size_t)(16+m)*128 + kc*32 + 8*q];
        #pragma unroll
        for (int rt=0; rt<2; rt++){
          short8 a = *(const short8*)&XsH[((w*2+rt)*16+m)*LSTRIDE + kc*32 + 8*q];
          ao[rt][0] = __builtin_amdgcn_mfma_f32_16x16x32_bf16(a, b0, ao[rt][0], 0,0,0);
          ao[rt][1] = __builtin_amdgcn_mfma_f32_16x16x32_bf16(a, b1, ao[rt][1], 0,0,0);
        }
      }
      #pragma unroll
      for (int rt=0; rt<2; rt++){
        #pragma unroll
        for (int nt=0; nt<2; nt++){
          #pragma unroll
          for (int i=0;i<4;i++){
            int rr = row0 + (w*2+rt)*16 + 4*q + i;
            if (rr<M) supY[(size_t)rr*32 + nt*16 + m] = f2bf(ao[rt][nt][i]);
          }
        }
      }
    }
  }
}

// -------- SpMM gather (contiguous per-node edges, 8-deep unroll) + fused BN stats --------
// (exact round-2 body: do NOT add tail code here — it wrecks regalloc of the gather loop)
__global__ __launch_bounds__(256) void k_spmm128(const unsigned short* __restrict__ sup,
    const unsigned int* __restrict__ sedge, const int* __restrict__ offs,
    unsigned short* __restrict__ h, int lbase, float* __restrict__ stL){
  int nl = threadIdx.x>>5;
  int node = blockIdx.x*8 + nl;
  int fq = threadIdx.x & 31;
  int p = offs[lbase+node], end = offs[lbase+node+1];
  float4 a0 = make_float4(0.f,0.f,0.f,0.f), a1 = a0, a2 = a0, a3 = a0;
  for (; p+7<end; p+=8){
    unsigned int ev[8];
    #pragma unroll
    for (int u=0;u<8;u++) ev[u] = __builtin_nontemporal_load(sedge+p+u);
    ushort4 sv[8];
    #pragma unroll
    for (int u=0;u<8;u++) sv[u] = *(const ushort4*)(sup + (size_t)(ev[u]&0xFFFFu)*128 + fq*4);
    #pragma unroll
    for (int u=0;u<8;u++){
      float w = __half2float(__ushort_as_half((unsigned short)(ev[u]>>16)));
      float4& a = (u&3)==0? a0 : (u&3)==1? a1 : (u&3)==2? a2 : a3;
      a.x += w*bf2f(sv[u].x); a.y += w*bf2f(sv[u].y);
      a.z += w*bf2f(sv[u].z); a.w += w*bf2f(sv[u].w);
    }
  }
  for (; p+3<end; p+=4){
    unsigned int e0 = __builtin_nontemporal_load(sedge+p);
    unsigned int e1 = __builtin_nontemporal_load(sedge+p+1);
    unsigned int e2 = __builtin_nontemporal_load(sedge+p+2);
    unsigned int e3 = __builtin_nontemporal_load(sedge+p+3);
    ushort4 s0 = *(const ushort4*)(sup + (size_t)(e0&0xFFFFu)*128 + fq*4);
    ushort4 s1 = *(const ushort4*)(sup + (size_t)(e1&0xFFFFu)*128 + fq*4);
    ushort4 s2 = *(const ushort4*)(sup + (size_t)(e2&0xFFFFu)*128 + fq*4);
    ushort4 s3 = *(const ushort4*)(sup + (size_t)(e3&0xFFFFu)*128 + fq*4);
    float w0 = __half2float(__ushort_as_half((unsigned short)(e0>>16)));
    float w1 = __half2float(__ushort_as_half((unsigned short)(e1>>16)));
    float w2 = __half2float(__ushort_as_half((unsigned short)(e2>>16)));
    float w3 = __half2float(__ushort_as_half((unsigned short)(e3>>16)));
    a0.x += w0*bf2f(s0.x); a0.y += w0*bf2f(s0.y); a0.z += w0*bf2f(s0.z); a0.w += w0*bf2f(s0.w);
    a1.x += w1*bf2f(s1.x); a1.y += w1*bf2f(s1.y); a1.z += w1*bf2f(s1.z); a1.w += w1*bf2f(s1.w);
    a2.x += w2*bf2f(s2.x); a2.y += w2*bf2f(s2.y); a2.z += w2*bf2f(s2.z); a2.w += w2*bf2f(s2.w);
    a3.x += w3*bf2f(s3.x); a3.y += w3*bf2f(s3.y); a3.z += w3*bf2f(s3.z); a3.w += w3*bf2f(s3.w);
  }
  for (; p<end; p++){
    unsigned int e0 = __builtin_nontemporal_load(sedge+p);
    float w0 = __half2float(__ushort_as_half((unsigned short)(e0>>16)));
    ushort4 s0 = *(const ushort4*)(sup + (size_t)(e0&0xFFFFu)*128 + fq*4);
    a0.x += w0*bf2f(s0.x); a0.y += w0*bf2f(s0.y); a0.z += w0*bf2f(s0.z); a0.w += w0*bf2f(s0.w);
  }
  a0.x+=a1.x+a2.x+a3.x; a0.y+=a1.y+a2.y+a3.y;
  a0.z+=a1.z+a2.z+a3.z; a0.w+=a1.w+a2.w+a3.w;
  ushort4 ov;
  ov.x=f2bf(a0.x); ov.y=f2bf(a0.y); ov.z=f2bf(a0.z); ov.w=f2bf(a0.w);
  *(ushort4*)(h + (size_t)node*128 + fq*4) = ov;
  __shared__ float sP[8][132], sQ[8][132];
  int f0 = fq*4;
  sP[nl][f0+0]=a0.x; sP[nl][f0+1]=a0.y; sP[nl][f0+2]=a0.z; sP[nl][f0+3]=a0.w;
  sQ[nl][f0+0]=a0.x*a0.x; sQ[nl][f0+1]=a0.y*a0.y; sQ[nl][f0+2]=a0.z*a0.z; sQ[nl][f0+3]=a0.w*a0.w;
  __syncthreads();
  if (threadIdx.x < 128){
    int f = threadIdx.x;
    float s=0.f, sq=0.f;
    #pragma unroll
    for (int n=0;n<8;n++){ s += sP[n][f]; sq += sQ[n][f]; }
    float* base = stL + (blockIdx.x & (NREP-1))*256;
    atomicAdd(&base[f], s); atomicAdd(&base[128+f], sq);
  }
}

// -------- output SpMM: bf16 [NN][32] sup rows, one cacheline/edge; fused BN stats tail --------
__global__ __launch_bounds__(256) void k_spmm_out(const unsigned short* __restrict__ sup,
    const unsigned int* __restrict__ sedge, const int* __restrict__ offs,
    float* __restrict__ h, int lbase, float* __restrict__ st8){
  int nl = threadIdx.x>>5;
  int node = blockIdx.x*8 + nl;
  int c = threadIdx.x & 31;
  bool act = c < OUTC;
  int p = offs[lbase+node], end = offs[lbase+node+1];
  float a0=0.f,a1=0.f,a2=0.f,a3=0.f;
  for (; p+7<end; p+=8){
    unsigned int ev[8];
    #pragma unroll
    for (int u=0;u<8;u++) ev[u] = __builtin_nontemporal_load(sedge+p+u);
    float sv[8];
    #pragma unroll
    for (int u=0;u<8;u++) sv[u] = bf2f(sup[(size_t)(ev[u]&0xFFFFu)*32 + c]);
    #pragma unroll
    for (int u=0;u<8;u++){
      float w = __half2float(__ushort_as_half((unsigned short)(ev[u]>>16)));
      if ((u&3)==0) a0 += w*sv[u];
      else if ((u&3)==1) a1 += w*sv[u];
      else if ((u&3)==2) a2 += w*sv[u];
      else a3 += w*sv[u];
    }
  }
  for (; p<end; p++){
    unsigned int e = __builtin_nontemporal_load(sedge+p);
    float w = __half2float(__ushort_as_half((unsigned short)(e>>16)));
    a0 += w*bf2f(sup[(size_t)(e&0xFFFFu)*32 + c]);
  }
  float v = a0+a1+a2+a3;
  if (act) h[(size_t)node*OUTC+c] = v;
  if (!act) v = 0.f;
  __shared__ float sS[8][33], sQ[8][33];
  sS[nl][c] = v; sQ[nl][c] = v*v;
  __syncthreads();
  if (threadIdx.x < 32){
    float s=0.f, sq=0.f;
    #pragma unroll
    for (int n=0;n<8;n++){ s += sS[n][c]; sq += sQ[n][c]; }
    if (c<OUTC){
      float* base = st8 + (blockIdx.x&7)*64;
      atomicAdd(&base[c], s); atomicAdd(&base[32+c], sq);
    }
  }
}

// ---------- fused: BN-normalize+ReLU + masked reduce; last block writes final output ----------
__global__ __launch_bounds__(256) void k_reduce(const float* __restrict__ xf,
    const float* __restrict__ st8, const float* __restrict__ gamma,
    const float* __restrict__ beta, const int* __restrict__ verts,
    const float* __restrict__ mw, float* __restrict__ acc8, int rpb,
    const float* __restrict__ mb, float* __restrict__ outp, int* __restrict__ tick,
    int nblocks){
  int c = threadIdx.x & 31, g = threadIdx.x >> 5;
  float scn=0.f, offc=0.f;
  if (c<OUTC){
    float s=0.f, sq=0.f;
    #pragma unroll
    for (int i=0;i<8;i++){ s += st8[i*64+c]; sq += st8[i*64+32+c]; }
    const float invN = 1.0f/NN;
    float m = s*invN;
    float var = sq*invN - m*m;
    scn = rsqrtf(var+BN_EPS)*gamma[c];
    offc = beta[c] - m*scn;
  }
  int r0 = blockIdx.x*rpb;
  int r1 = min(NN, r0+rpb);
  float s=0.f;
  for (int r=r0+g; r<r1; r+=8){
    float m = mw[verts[r]];
    if (c<OUTC){
      float v = fmaxf(fmaf(xf[(size_t)r*OUTC+c], scn, offc), 0.f);
      s += m * v;
    }
  }
  __shared__ float sh[256];
  sh[threadIdx.x]=s; __syncthreads();
  if (threadIdx.x<32){
    #pragma unroll
    for (int i=1;i<8;i++) s += sh[threadIdx.x + i*32];
    if (c<OUTC) atomicAdd(&acc8[(blockIdx.x&7)*32 + c], s);
  }
  // last-block final combine (replaces k_final)
  __syncthreads();
  __shared__ int lastf;
  if (threadIdx.x==0){
    __threadfence();
    int tk = __hip_atomic_fetch_add(tick, 1, __ATOMIC_ACQ_REL, __HIP_MEMORY_SCOPE_AGENT);
    lastf = (tk == nblocks-1);
  }
  __syncthreads();
  if (lastf && threadIdx.x < 32 && c < OUTC){
    float s2=0.f;
    #pragma unroll
    for (int gg=0; gg<8; gg++)
      s2 += __hip_atomic_load(&acc8[gg*32+c], __ATOMIC_RELAXED, __HIP_MEMORY_SCOPE_AGENT);
    outp[c] = sigm(s2+mb[c]);
  }
}

// ---------------- host ----------------
extern "C" void kernel_launch(void* const* d_in, const int* in_sizes, int n_in,
                              void* d_out, int out_size, void* d_ws, size_t ws_size,
                              hipStream_t stream){
  const int*   verts = (const int*)d_in[0];
  const int*   ei    = (const int*)d_in[1];
  const float* ew    = (const float*)d_in[2];
  const float* emb   = (const float*)d_in[3];
  const float* wh    = (const float*)d_in[4];
  const float* w_out = (const float*)d_in[6];
  const float* bng_h = (const float*)d_in[8];
  const float* bnb_h = (const float*)d_in[9];
  const float* bng_o = (const float*)d_in[10];
  const float* bnb_o = (const float*)d_in[11];
  const float* tewl  = (const float*)d_in[12];
  const float* tewc  = (const float*)d_in[13];
  const float* teb   = (const float*)d_in[14];
  const float* maskw = (const float*)d_in[15];
  const float* maskb = (const float*)d_in[16];
  float* out = (float*)d_out;

  char* ws = (char*)d_ws;
  size_t off=0;
  auto alloc=[&](size_t bytes)->char*{ char* p = ws+off; off += (bytes+255)&~(size_t)255; return p; };
  unsigned int* sedge = (unsigned int*)alloc(sizeof(int)*LE);   // 22.4 MB
  int*   offs   = (int*)  alloc(sizeof(int)*(LN+1));            // 1.4 MB
  int*   Gm     = (int*)  alloc(sizeof(int)*LL*NBLK*GMS);       // 1.1 MB
  int*   S      = (int*)  alloc(sizeof(int)*(SCN+1));           // 1.1 MB
  int*   bsums  = (int*)  alloc(sizeof(int)*1024);
  unsigned short* xbf   = (unsigned short*)alloc(sizeof(short)*NN*DIM); // 12.8 MB
  unsigned short* supbf = (unsigned short*)alloc(sizeof(short)*NN*DIM); // 12.8 MB
  unsigned short* hbf   = (unsigned short*)alloc(sizeof(short)*NN*DIM); // 12.8 MB
  unsigned short* supO  = (unsigned short*)alloc(sizeof(short)*NN*32);  // 3.2 MB bf16 [NN][32]
  unsigned short* Wt = (unsigned short*)alloc(sizeof(short)*18*DIM*DIM);
  unsigned short* WtO = (unsigned short*)alloc(sizeof(short)*32*DIM);   // 8 KB
  float* stats  = (float*)alloc(sizeof(float)*STATSZ);
  float* ostat8 = stats + 6*NREP*256;  // [8][64]
  float* racc8  = ostat8 + 8*64;       // [8][32]
  int*   tick   = (int*)(racc8 + 8*32);
  unsigned int*  btmpP = (unsigned int*)xbf;
  unsigned char* btmpD = (unsigned char*)hbf;

  // --- fused prologue + LDS-atomic counting sort (scan3 folded into consumers) ---
  k_pre<<<2665,256,0,stream>>>(wh, tewl, tewc, w_out, Wt, WtO, ei, Gm, stats);
  int nsb = (SCN+4095)/4096;  // 68
  k_scan1p<<<nsb,256,0,stream>>>(Gm, S, bsums);
  k_scan2<<<1,1024,0,stream>>>(bsums, nsb);
  k_bscatter<<<LL*NBLK,256,0,stream>>>(ei, ew, S, bsums, Gm, btmpP, btmpD);
  k_fsort<<<LL*NBUK,256,0,stream>>>(btmpP, btmpD, S, bsums, sedge, offs);

  // --- 6 hidden layers; sup for layer i+1 (or output) computed inside gate2 of layer i ---
  k_gemm_sup_emb<<<(NN+31)/32,256,0,stream>>>(verts, emb, Wt, supbf, xbf, NN);
  for (int i=0;i<6;i++){
    int j = (i==0)?5:(i-1);
    float* stL = stats + i*NREP*256;
    k_spmm128<<<NN/8,256,0,stream>>>(supbf, sedge, offs, hbf, i*NN, stL);
    if (i<5)
      k_gemm_gate2<1><<<(NN+63)/64,256,0,stream>>>(hbf, stL,
          bng_h+(size_t)i*DIM, bnb_h+(size_t)i*DIM,
          Wt + (size_t)(6+j)*DIM*DIM, Wt + (size_t)(12+j)*DIM*DIM,
          Wt + (size_t)(i+1)*DIM*DIM, teb + (size_t)j*DIM, xbf, supbf, NN);
    else
      k_gemm_gate2<2><<<(NN+63)/64,256,0,stream>>>(hbf, stL,
          bng_h+(size_t)i*DIM, bnb_h+(size_t)i*DIM,
          Wt + (size_t)(6+j)*DIM*DIM, Wt + (size_t)(12+j)*DIM*DIM,
          WtO, teb + (size_t)j*DIM, xbf, supO, NN);
  }

  // --- output layer: spmm on bf16 [NN][32] sup; fused stats; reduce+final merged ---
  k_spmm_out<<<NN/8,256,0,stream>>>(supO, sedge, offs, (float*)hbf, 6*NN, ostat8);
  float* bufO = (float*)hbf;
  k_reduce<<<512,256,0,stream>>>(bufO, ostat8, bng_o, bnb_o, verts, maskw, racc8, 98,
                                 maskb, out, tick, 512);
}